// Round 9
// baseline (743.829 us; speedup 1.0000x reference)
//
#include <hip/hip_runtime.h>
#include <hip/hip_bf16.h>
#include <hip/hip_fp8.h>
#include <cstdint>
#include <cstddef>
#include <cstring>

typedef __hip_bfloat16 bf16;
typedef unsigned char fp8;                                  // e4m3 storage
typedef __attribute__((ext_vector_type(8))) short short8;   // 8 bf16 (MFMA A/B frag)
typedef __attribute__((ext_vector_type(4))) float f32x4;    // MFMA C/D frag
typedef __attribute__((ext_vector_type(2))) float f32x2;

#define NSF 128
#define BN_EPS 1e-3f
#define NR 4            // src ranges per node
#define SCK 2048        // elements per scan block

// ---------------- CSR build: 1 atomic per edge ----------------

__global__ void passA_kernel(const int* __restrict__ ei, int* __restrict__ fill,
                             int* __restrict__ loc, int E, int n, int rsize) {
    int idx = blockIdx.x * blockDim.x + threadIdx.x;
    if (idx < E) {
        int r = ei[idx];
        int c = ei[E + idx];
        int slot = c * NR + r / rsize;
        loc[idx] = atomicAdd(&fill[slot], 1);
    } else if (idx < E + n) {
        int i = idx - E;
        int slot = i * NR + i / rsize;
        loc[idx] = atomicAdd(&fill[slot], 1);
    }
}

// ---- hierarchical exclusive scan of fill -> row_ptr ----

__global__ void scan1_kernel(const int* __restrict__ cnt, int* __restrict__ blksum, int total) {
    __shared__ int red[256];
    int base = blockIdx.x * SCK + threadIdx.x * 8;
    int s = 0;
    #pragma unroll
    for (int i = 0; i < 8; ++i) {
        int idx = base + i;
        if (idx < total) s += cnt[idx];
    }
    red[threadIdx.x] = s;
    __syncthreads();
    for (int off2 = 128; off2 > 0; off2 >>= 1) {
        if (threadIdx.x < off2) red[threadIdx.x] += red[threadIdx.x + off2];
        __syncthreads();
    }
    if (threadIdx.x == 0) blksum[blockIdx.x] = red[0];
}

__global__ void scan2_kernel(int* __restrict__ blksum, int* __restrict__ row_ptr,
                             int nblk, int total) {
    __shared__ int part[256];
    int tid = threadIdx.x;
    int v = (tid < nblk) ? blksum[tid] : 0;
    part[tid] = v;
    __syncthreads();
    for (int off2 = 1; off2 < 256; off2 <<= 1) {
        int t = (tid >= off2) ? part[tid - off2] : 0;
        __syncthreads();
        part[tid] += t;
        __syncthreads();
    }
    if (tid < nblk) blksum[tid] = part[tid] - v;
    if (tid == 255) row_ptr[total] = part[255];
}

__global__ void scan3_kernel(const int* __restrict__ cnt, const int* __restrict__ blkoff,
                             int* __restrict__ row_ptr, int total) {
    __shared__ int part[256];
    int tid = threadIdx.x;
    int base = blockIdx.x * SCK + tid * 8;
    int loc[8]; int s = 0;
    #pragma unroll
    for (int i = 0; i < 8; ++i) {
        int idx = base + i;
        loc[i] = (idx < total) ? cnt[idx] : 0;
        s += loc[i];
    }
    part[tid] = s;
    __syncthreads();
    for (int off2 = 1; off2 < 256; off2 <<= 1) {
        int t = (tid >= off2) ? part[tid - off2] : 0;
        __syncthreads();
        part[tid] += t;
        __syncthreads();
    }
    int run = blkoff[blockIdx.x] + part[tid] - s;
    #pragma unroll
    for (int i = 0; i < 8; ++i) {
        int idx = base + i;
        if (idx < total) { row_ptr[idx] = run; run += loc[i]; }
    }
}

// passB: scatter without atomics; packed edge record {src, w_bits}
__global__ void passB_kernel(const int* __restrict__ ei, const float* __restrict__ ea,
                             const int* __restrict__ row_ptr, const int* __restrict__ loc,
                             int2* __restrict__ e8, int* __restrict__ csr_col,
                             int E, int n, int rsize) {
    int idx = blockIdx.x * blockDim.x + threadIdx.x;
    if (idx < E) {
        int r = ei[idx];
        int c = ei[E + idx];
        int slot = c * NR + r / rsize;
        int p = row_ptr[slot] + loc[idx];
        int2 rec; rec.x = r; rec.y = __float_as_int(ea[idx]);
        e8[p] = rec;
        csr_col[p] = c;
    } else if (idx < E + n) {
        int i = idx - E;
        int slot = i * NR + i / rsize;
        int p = row_ptr[slot] + loc[idx];
        int2 rec; rec.x = i; rec.y = __float_as_int(1.0f);
        e8[p] = rec;
        csr_col[p] = i;
    }
}

__global__ void degdinv_kernel(const int* __restrict__ row_ptr, const int2* __restrict__ e8,
                               float* __restrict__ dinv, int n) {
    int node = blockIdx.x * blockDim.x + threadIdx.x;
    if (node < n) {
        int s = row_ptr[node * NR], e = row_ptr[(node + 1) * NR];
        float d = 0.0f;
        for (int j = s; j < e; ++j) d += __int_as_float(e8[j].y);
        dinv[node] = (d > 0.0f) ? rsqrtf(d) : 0.0f;
    }
}

__global__ void normw_kernel(const float* __restrict__ dinv, const int* __restrict__ csr_col,
                             int2* __restrict__ e8, int EN) {
    int p = blockIdx.x * blockDim.x + threadIdx.x;
    if (p < EN) {
        int2 rec = e8[p];
        float w = dinv[rec.x] * __int_as_float(rec.y) * dinv[csr_col[p]];
        ((int*)e8)[2 * p + 1] = __float_as_int(w);
    }
}

// ---------------- output-type helpers (HW fp8 cvt) ----------------

__device__ inline void store_val(bf16* C, size_t idx, float a) {
    C[idx] = __float2bfloat16(a);
}
__device__ inline void store_val(fp8* C, size_t idx, float a) {
    int packed = __builtin_amdgcn_cvt_pk_fp8_f32(a, a, 0, false);
    C[idx] = (fp8)(packed & 0xff);
}

// ---------------- fused prep: zero fill[] + x->fp8 + all W->Wt(bf16), one launch ----------------
__global__ void prep_kernel(int* __restrict__ fill, int total,
                            const float* __restrict__ x, fp8* __restrict__ xq, int xcnt,
                            const float* __restrict__ W0, const float* __restrict__ W1,
                            const float* __restrict__ W2, const float* __restrict__ W3,
                            const float* __restrict__ W4,
                            bf16* __restrict__ wtbuf, int wtelems) {
    int idx = blockIdx.x * blockDim.x + threadIdx.x;
    if (idx < total) { fill[idx] = 0; return; }
    idx -= total;
    if (idx < xcnt) {
        store_val(xq, idx, x[idx]);
        return;
    }
    int widx = idx - xcnt;
    if (widx >= wtelems) return;
    // layer boundaries (cumulative K*N): 32768, 163840, 294912, 327680, 344064
    const float* W; int K, off;
    if (widx < 32768)       { W = W0; K = 128; off = 0; }
    else if (widx < 163840) { W = W1; K = 256; off = 32768; }
    else if (widx < 294912) { W = W2; K = 512; off = 163840; }
    else if (widx < 327680) { W = W3; K = 256; off = 294912; }
    else                    { W = W4; K = 128; off = 327680; }
    int N2;
    if (widx < 32768) N2 = 256; else if (widx < 163840) N2 = 512;
    else if (widx < 294912) N2 = 256; else N2 = 128;
    int l = widx - off;
    int nn = l / K, kk = l % K;
    wtbuf[widx] = __float2bfloat16(W[(size_t)kk * N2 + nn]);
}

// ---------------- direct global->LDS 16B staging ----------------

__device__ inline void gl_lds16(const bf16* g, bf16* l) {
    __builtin_amdgcn_global_load_lds(
        (const __attribute__((address_space(1))) void*)g,
        (__attribute__((address_space(3))) void*)l,
        16, 0, 0);
}

// ---------------- MFMA GEMM (64x128 tile, BK=64 dual-stage): C = A @ Wt^T ----------------
// mode 0: raw store; mode 1: sigmoid(BN(acc+bias))

template <typename OT>
__global__ __launch_bounds__(256) void mfma_gemm_kernel(
    const bf16* __restrict__ A, const bf16* __restrict__ Wt,
    OT* __restrict__ C, int M, int K, int N, int mode,
    const float* __restrict__ bias, const float* __restrict__ g,
    const float* __restrict__ be, const float* __restrict__ m,
    const float* __restrict__ v) {
    __shared__ bf16 As[2][64][32];
    __shared__ bf16 Bs[2][128][32];
    int m0 = blockIdx.x * 64;
    int n0 = blockIdx.y * 128;
    int tid = threadIdx.x;
    int wave = tid >> 6, lane = tid & 63;
    int lrow = lane & 15, quad = lane >> 4;

    f32x4 acc[4][2] = {};   // [m-tile][n-tile]

    int srow = lane >> 2;
    int sseg = lane & 3;
    int am = wave * 16 + srow;
    int bn = wave * 32 + srow;
    bool aok = (m0 + am) < M;

    for (int k0 = 0; k0 < K; k0 += 64) {
        if (aok) {
            gl_lds16(A + (size_t)(m0 + am) * K + k0 + sseg * 8,      &As[0][am][sseg * 8]);
            gl_lds16(A + (size_t)(m0 + am) * K + k0 + 32 + sseg * 8, &As[1][am][sseg * 8]);
        }
        gl_lds16(Wt + (size_t)(n0 + bn) * K + k0 + sseg * 8,           &Bs[0][bn][sseg * 8]);
        gl_lds16(Wt + (size_t)(n0 + bn) * K + k0 + 32 + sseg * 8,      &Bs[1][bn][sseg * 8]);
        gl_lds16(Wt + (size_t)(n0 + bn + 16) * K + k0 + sseg * 8,      &Bs[0][bn + 16][sseg * 8]);
        gl_lds16(Wt + (size_t)(n0 + bn + 16) * K + k0 + 32 + sseg * 8, &Bs[1][bn + 16][sseg * 8]);
        __syncthreads();

        #pragma unroll
        for (int ks = 0; ks < 2; ++ks) {
            short8 afrag[4], bfrag[2];
            #pragma unroll
            for (int mt = 0; mt < 4; ++mt)
                afrag[mt] = *(const short8*)(&As[ks][mt * 16 + lrow][quad * 8]);
            #pragma unroll
            for (int nt = 0; nt < 2; ++nt)
                bfrag[nt] = *(const short8*)(&Bs[ks][wave * 32 + nt * 16 + lrow][quad * 8]);
            #pragma unroll
            for (int mt = 0; mt < 4; ++mt)
                #pragma unroll
                for (int nt = 0; nt < 2; ++nt)
                    acc[mt][nt] = __builtin_amdgcn_mfma_f32_16x16x32_bf16(
                        afrag[mt], bfrag[nt], acc[mt][nt], 0, 0, 0);
        }
        __syncthreads();
    }
    // C/D: col = lane&15, row = quad*4 + reg
    #pragma unroll
    for (int nt = 0; nt < 2; ++nt) {
        int gn = n0 + wave * 32 + nt * 16 + lrow;
        float bsc = 0.0f, scale = 1.0f, mean = 0.0f, beta = 0.0f;
        if (mode == 1) {
            bsc = bias[gn];
            scale = g[gn] * rsqrtf(v[gn] + BN_EPS);
            mean = m[gn];
            beta = be[gn];
        }
        #pragma unroll
        for (int mt = 0; mt < 4; ++mt) {
            #pragma unroll
            for (int rr = 0; rr < 4; ++rr) {
                int gm = m0 + mt * 16 + quad * 4 + rr;
                if (gm < M) {
                    float a = acc[mt][nt][rr];
                    if (mode == 1) {
                        a = (a + bsc - mean) * scale + beta;
                        a = 1.0f / (1.0f + __expf(-a));
                    }
                    store_val(C, (size_t)gm * N + gn, a);
                }
            }
        }
    }
}

// ---------------- fp8 aggregation: LDS-staged records + 2-deep pipelined gathers ----------------
// Round-1 structure (known best for VEC2 / whole-range).

template <int VEC> struct F8Vec;
template <> struct F8Vec<2> { typedef unsigned short T; };
template <> struct F8Vec<4> { typedef unsigned int T; };

__device__ inline void fma_f8(unsigned short q, float w, float* acc) {
    f32x2 lo = __builtin_amdgcn_cvt_pk_f32_fp8((unsigned int)q, false);
    acc[0] += w * lo.x;
    acc[1] += w * lo.y;
}
__device__ inline void fma_f8(unsigned int q, float w, float* acc) {
    f32x2 lo = __builtin_amdgcn_cvt_pk_f32_fp8(q, false);
    f32x2 hi = __builtin_amdgcn_cvt_pk_f32_fp8(q, true);
    acc[0] += w * lo.x;
    acc[1] += w * lo.y;
    acc[2] += w * hi.x;
    acc[3] += w * hi.y;
}

#define AGG_GATHER_BODY(SLO, SHI)                                            \
    for (int cs = (SLO); cs < (SHI); cs += 64) {                             \
        int cnt = (SHI) - cs; if (cnt > 64) cnt = 64;                        \
        int2 r0; r0.x = 0; r0.y = 0;                                         \
        if (lane < cnt) r0 = e8[cs + lane];                                  \
        recs[wave][lane] = r0;                                               \
        asm volatile("s_waitcnt vmcnt(0) lgkmcnt(0)" ::: "memory");          \
        int npad = (cnt + 15) & ~15;                                         \
        T qA[8], qB[8];                                                      \
        float wA[8], wB[8];                                                  \
        LOADG(qA, wA, 0)                                                     \
        LOADG(qB, wB, 8)                                                     \
        for (int j0 = 16; j0 < npad; j0 += 16) {                             \
            CONSUME(qA, wA)                                                  \
            LOADG(qA, wA, j0)                                                \
            CONSUME(qB, wB)                                                  \
            LOADG(qB, wB, j0 + 8)                                            \
        }                                                                    \
        CONSUME(qA, wA)                                                      \
        CONSUME(qB, wB)                                                      \
    }

#define LOADG(Q, WV, J0)                                                     \
    _Pragma("unroll")                                                        \
    for (int u = 0; u < 8; ++u) {                                            \
        int2 rec = recs[wave][(J0) + u];                                     \
        WV[u] = __int_as_float(rec.y);                                       \
        Q[u] = *(const T*)(hw + ((unsigned int)rec.x * dfeat + base));       \
    }
#define CONSUME(Q, WV)                                                       \
    _Pragma("unroll")                                                        \
    for (int u = 0; u < 8; ++u) fma_f8(Q[u], WV[u], acc);

template <int VEC>
__global__ __launch_bounds__(256) void agg_fp8_kernel(
    const fp8* __restrict__ hw,
    const int* __restrict__ row_ptr, const int2* __restrict__ e8,
    const float* __restrict__ bias,
    const float* __restrict__ g, const float* __restrict__ be,
    const float* __restrict__ m, const float* __restrict__ v,
    bf16* __restrict__ out, int n, int mode) {
    typedef typename F8Vec<VEC>::T T;
    const int dfeat = VEC * 64;
    __shared__ int2 recs[4][64];
    int wave = threadIdx.x >> 6;
    int lane = threadIdx.x & 63;
    int node = blockIdx.x * 4 + wave;
    if (node >= n) return;
    int s = row_ptr[node * NR], e = row_ptr[(node + 1) * NR];
    float acc[VEC];
    #pragma unroll
    for (int i = 0; i < VEC; ++i) acc[i] = 0.0f;
    const unsigned int base = (unsigned int)lane * VEC;

    AGG_GATHER_BODY(s, e)

    #pragma unroll
    for (int i = 0; i < VEC; ++i) {
        int f = (int)base + i;
        float a = acc[i];
        if (mode != 0) {
            a += bias[f];
            if (mode == 1) {
                float scale = g[f] * rsqrtf(v[f] + BN_EPS);
                a = (a - m[f]) * scale + be[f];
            }
            a = 1.0f / (1.0f + __expf(-a));
        }
        out[(size_t)node * dfeat + f] = __float2bfloat16(a);
    }
}

// ---------------- bucket-major fp8 aggregation (round 25, L2-residency) ----------------
// Dispatch processes buckets [bstart, bstart+nbuck) bucket-major: blockIdx.x =
// bucketRel * nblk + nodeblock, so concurrently-running blocks share one source
// bucket (working set ~1.25 MB for VEC4 -> per-XCD L2-resident). store=1: plain
// f32 store (first bucket); store=0: atomicAdd into accumulator.

template <int VEC>
__global__ __launch_bounds__(256) void agg_bucket_kernel(
    const fp8* __restrict__ hw,
    const int* __restrict__ row_ptr, const int2* __restrict__ e8,
    float* __restrict__ accb, int n, int bstart, int store) {
    typedef typename F8Vec<VEC>::T T;
    const int dfeat = VEC * 64;
    __shared__ int2 recs[4][64];
    int nblk = (n + 3) / 4;
    int brel = blockIdx.x / nblk;
    int nb = blockIdx.x - brel * nblk;
    int bkt = bstart + brel;
    int wave = threadIdx.x >> 6;
    int lane = threadIdx.x & 63;
    int node = nb * 4 + wave;
    if (node >= n) return;
    int s = row_ptr[node * NR + bkt], e = row_ptr[node * NR + bkt + 1];
    float acc[VEC];
    #pragma unroll
    for (int i = 0; i < VEC; ++i) acc[i] = 0.0f;
    const unsigned int base = (unsigned int)lane * VEC;

    AGG_GATHER_BODY(s, e)

    float* ap = accb + (size_t)node * dfeat + base;
    if (store) {
        #pragma unroll
        for (int i = 0; i < VEC; ++i) ap[i] = acc[i];
    } else {
        #pragma unroll
        for (int i = 0; i < VEC; ++i) atomicAdd(&ap[i], acc[i]);
    }
}

#undef LOADG
#undef CONSUME
#undef AGG_GATHER_BODY

// epilogue: f32 accumulator -> activation -> bf16 out
__global__ void agg_epi_kernel(const float* __restrict__ accb,
                               const float* __restrict__ bias,
                               const float* __restrict__ g, const float* __restrict__ be,
                               const float* __restrict__ m, const float* __restrict__ v,
                               bf16* __restrict__ out, int n, int dfeat, int mode) {
    int idx = blockIdx.x * blockDim.x + threadIdx.x;
    if (idx >= n * dfeat) return;
    int f = idx % dfeat;
    float a = accb[idx];
    if (mode != 0) {
        a += bias[f];
        if (mode == 1) {
            float scale = g[f] * rsqrtf(v[f] + BN_EPS);
            a = (a - m[f]) * scale + be[f];
        }
        a = 1.0f / (1.0f + __expf(-a));
    }
    out[idx] = __float2bfloat16(a);
}

// ---------------- final h^T h via MFMA ----------------
#define TPAD 8

__global__ __launch_bounds__(256) void htht_mfma_kernel(
    const bf16* __restrict__ h, float* __restrict__ partial, int n) {
    __shared__ bf16 hsT[128][32 + TPAD];
    int b = blockIdx.x;
    int tid = threadIdx.x;
    int wave = tid >> 6, lane = tid & 63;
    int lrow = lane & 15, quad = lane >> 4;

    f32x4 acc[2][8] = {};

    int kk = tid >> 3;
    int seg = tid & 7;

    for (int kt = 0; kt < 8; ++kt) {
        int k0 = b * 256 + kt * 32;
        #pragma unroll
        for (int s2 = 0; s2 < 2; ++s2) {
            int fs = (seg + s2 * 8) * 8;
            int gk = k0 + kk;
            uint4 q; q.x = q.y = q.z = q.w = 0u;
            if (gk < n) q = *(const uint4*)(h + (size_t)gk * 128 + fs);
            const unsigned short* u = (const unsigned short*)&q;
            #pragma unroll
            for (int i = 0; i < 8; ++i)
                *((unsigned short*)&hsT[fs + i][kk]) = u[i];
        }
        __syncthreads();
        short8 af0 = *(const short8*)(&hsT[wave * 32 + lrow][quad * 8]);
        short8 af1 = *(const short8*)(&hsT[wave * 32 + 16 + lrow][quad * 8]);
        #pragma unroll
        for (int t = 0; t < 8; ++t) {
            short8 bfrag = *(const short8*)(&hsT[t * 16 + lrow][quad * 8]);
            acc[0][t] = __builtin_amdgcn_mfma_f32_16x16x32_bf16(af0, bfrag, acc[0][t], 0, 0, 0);
            acc[1][t] = __builtin_amdgcn_mfma_f32_16x16x32_bf16(af1, bfrag, acc[1][t], 0, 0, 0);
        }
        __syncthreads();
    }
    float* p = partial + (size_t)b * 16384;
    #pragma unroll
    for (int a_ = 0; a_ < 2; ++a_) {
        #pragma unroll
        for (int t = 0; t < 8; ++t) {
            #pragma unroll
            for (int rr = 0; rr < 4; ++rr) {
                int gm = wave * 32 + a_ * 16 + quad * 4 + rr;
                int gn = t * 16 + lrow;
                p[gm * 128 + gn] = acc[a_][t][rr];
            }
        }
    }
}

__global__ void reduce_kernel(const float* __restrict__ partial, float* __restrict__ out, int nchunks) {
    int idx = blockIdx.x * blockDim.x + threadIdx.x;
    float s = 0.0f;
    for (int c = 0; c < nchunks; ++c) s += partial[(size_t)c * 16384 + idx];
    int i = idx / 128, j = idx % 128;
    out[idx] = (i == j) ? 0.0f : s;
}

// ---------------- launch ----------------
extern "C" void kernel_launch(void* const* d_in, const int* in_sizes, int n_in,
                              void* d_out, int out_size, void* d_ws, size_t ws_size,
                              hipStream_t stream) {
    const float* x  = (const float*)d_in[0];
    const int*   ei = (const int*)d_in[1];
    const float* ea = (const float*)d_in[2];
    const float* W[5];  const float* bvec[5];
    for (int l = 0; l < 5; ++l) { W[l] = (const float*)d_in[3 + 2 * l]; bvec[l] = (const float*)d_in[4 + 2 * l]; }
    const float* g[4]; const float* be[4]; const float* mm[4]; const float* vv[4];
    for (int l = 0; l < 4; ++l) {
        g[l]  = (const float*)d_in[13 + 4 * l];
        be[l] = (const float*)d_in[14 + 4 * l];
        mm[l] = (const float*)d_in[15 + 4 * l];
        vv[l] = (const float*)d_in[16 + 4 * l];
    }
    const int n = in_sizes[0] / NSF;        // 20000
    const int E = in_sizes[1] / 2;          // 500000
    const int EN = E + n;
    const int rsize = (n + NR - 1) / NR;
    const int total = n * NR;
    const int nscan = (total + SCK - 1) / SCK;
    const int dims[6] = {128, 256, 512, 256, 128, 128};
    const int wtoff[5] = {0, 32768, 163840, 294912, 327680};
    const int wtelems = 344064;

    // workspace layout (256B aligned); ~69 MB (identical to known-good round-1 layout)
    auto align = [](size_t o) { return (o + 255) & ~(size_t)255; };
    size_t off = 0;
    float* dinv    = (float*)((char*)d_ws + off); off = align(off + (size_t)n * 4);
    int*   fill    = (int*)  ((char*)d_ws + off); off = align(off + (size_t)total * 4);
    int*   row_ptr = (int*)  ((char*)d_ws + off); off = align(off + ((size_t)total + 1) * 4);
    int*   blksum  = (int*)  ((char*)d_ws + off); off = align(off + (size_t)256 * 4);
    int*   locb    = (int*)  ((char*)d_ws + off); off = align(off + (size_t)EN * 4);
    int2*  e8      = (int2*) ((char*)d_ws + off); off = align(off + (size_t)EN * 8);
    int*   csr_col = (int*)  ((char*)d_ws + off); off = align(off + (size_t)EN * 4);
    bf16*  wtbuf   = (bf16*) ((char*)d_ws + off); off = align(off + (size_t)wtelems * 2);
    fp8*   xq      = (fp8*)  ((char*)d_ws + off); off = align(off + (size_t)n * 128);
    bf16*  hbuf    = (bf16*) ((char*)d_ws + off); off = align(off + (size_t)n * 512 * 2);
    bf16*  abuf    = (bf16*) ((char*)d_ws + off); off = align(off + (size_t)n * 512 * 2);
    fp8*   f8buf   = (fp8*)  ((char*)d_ws + off); off = align(off + (size_t)n * 256);
    const int KCH = (20000 + 255) / 256;    // 79
    float* partial = (float*)((char*)d_ws + off); off = align(off + (size_t)KCH * 16384 * 4);

    // fused prep: zero fill + x->fp8 + W->Wt (one launch, independent of edges)
    {
        int xcnt = n * 128;
        int items = total + xcnt + wtelems;
        prep_kernel<<<(items + 255) / 256, 256, 0, stream>>>(fill, total, x, xq, xcnt,
            W[0], W[1], W[2], W[3], W[4], wtbuf, wtelems);
    }

    // CSR build (1 atomic/edge, packed edge records)
    passA_kernel<<<(EN + 255) / 256, 256, 0, stream>>>(ei, fill, locb, E, n, rsize);
    scan1_kernel<<<nscan, 256, 0, stream>>>(fill, blksum, total);
    scan2_kernel<<<1, 256, 0, stream>>>(blksum, row_ptr, nscan, total);
    scan3_kernel<<<nscan, 256, 0, stream>>>(fill, blksum, row_ptr, total);
    passB_kernel<<<(EN + 255) / 256, 256, 0, stream>>>(ei, ea, row_ptr, locb,
                                                       e8, csr_col, E, n, rsize);
    degdinv_kernel<<<(n + 255) / 256, 256, 0, stream>>>(row_ptr, e8, dinv, n);
    normw_kernel<<<(EN + 255) / 256, 256, 0, stream>>>(dinv, csr_col, e8, EN);

    int ablocks = (n + 3) / 4;
    auto gemm_bf16 = [&](const bf16* A, int l, bf16* C, int mode) {
        int K = dims[l], N = dims[l + 1];
        dim3 gg((n + 63) / 64, N / 128);
        int bi = (l < 4) ? l : 0;
        mfma_gemm_kernel<bf16><<<gg, 256, 0, stream>>>(A, wtbuf + wtoff[l], C, n, K, N, mode,
                                                       bvec[l], g[bi], be[bi], mm[bi], vv[bi]);
    };
    auto gemm_fp8 = [&](const bf16* A, int l, fp8* C, int mode) {
        int K = dims[l], N = dims[l + 1];
        dim3 gg((n + 63) / 64, N / 128);
        int bi = (l < 4) ? l : 0;
        mfma_gemm_kernel<fp8><<<gg, 256, 0, stream>>>(A, wtbuf + wtoff[l], C, n, K, N, mode,
                                                      bvec[l], g[bi], be[bi], mm[bi], vv[bi]);
    };
    // bucket-major VEC4 agg chain: store bucket 0, atomicAdd buckets 1..3, epilogue
    auto agg4_bucketed = [&](const fp8* in, float* accb, bf16* out,
                             const float* bias, const float* gg2, const float* bb,
                             const float* mm2, const float* vv2, int mode) {
        agg_bucket_kernel<4><<<ablocks, 256, 0, stream>>>(in, row_ptr, e8, accb, n, 0, 1);
        agg_bucket_kernel<4><<<3 * ablocks, 256, 0, stream>>>(in, row_ptr, e8, accb, n, 1, 0);
        agg_epi_kernel<<<(n * 256 + 255) / 256, 256, 0, stream>>>(accb, bias, gg2, bb, mm2, vv2,
                                                                  out, n, 256, mode);
    };

    // L1 (128->256): agg-first fp8 128 (xq), GEMM1 fused act -> fp8 h1
    agg_fp8_kernel<2><<<ablocks, 256, 0, stream>>>(xq, row_ptr, e8,
        bvec[0], bvec[0], bvec[0], bvec[0], bvec[0], abuf, n, 0);
    gemm_fp8(abuf, 0, f8buf, 1);
    // L2 (256->512): bucket-major agg fp8 256 (h1) -> bf16 (acc = hbuf, free until L2 gemm)
    agg4_bucketed(f8buf, (float*)hbuf, abuf, bvec[1], bvec[1], bvec[1], bvec[1], bvec[1], 0);
    gemm_bf16(abuf, 1, hbuf, 1);
    // L3 (512->256): GEMM3 raw -> fp8 hw3, bucket-major agg + bias+BN+sigmoid (acc = hbuf, freed by gemm)
    gemm_fp8(hbuf, 2, f8buf, 0);
    agg4_bucketed(f8buf, (float*)hbuf, abuf, bvec[2], g[2], be[2], mm[2], vv[2], 1);
    // L4 (256->128): GEMM4 raw -> fp8 hw4, agg-last fp8 128 + bias+BN+sigmoid -> bf16 h4
    gemm_fp8(abuf, 3, f8buf, 0);
    agg_fp8_kernel<2><<<ablocks, 256, 0, stream>>>(f8buf, row_ptr, e8,
        bvec[3], g[3], be[3], mm[3], vv[3], hbuf, n, 1);
    // L5 (128->128): GEMM5 raw -> fp8 hw5, agg-last fp8 128 + bias+sigmoid -> bf16 h5
    gemm_fp8(hbuf, 4, f8buf, 0);
    agg_fp8_kernel<2><<<ablocks, 256, 0, stream>>>(f8buf, row_ptr, e8,
        bvec[4], bvec[4], bvec[4], bvec[4], bvec[4], abuf, n, 2);

    // final h^T h with zeroed diagonal (MFMA)
    htht_mfma_kernel<<<KCH, 256, 0, stream>>>(abuf, partial, n);
    reduce_kernel<<<16384 / 256, 256, 0, stream>>>(partial, (float*)d_out, KCH);
}

// Round 10
// 426.270 us; speedup vs baseline: 1.7450x; 1.7450x over previous
//
#include <hip/hip_runtime.h>
#include <hip/hip_bf16.h>
#include <hip/hip_fp8.h>
#include <cstdint>
#include <cstddef>
#include <cstring>

typedef __hip_bfloat16 bf16;
typedef unsigned char fp8;                                  // e4m3 storage
typedef __attribute__((ext_vector_type(8))) short short8;   // 8 bf16 (MFMA A/B frag)
typedef __attribute__((ext_vector_type(4))) float f32x4;    // MFMA C/D frag
typedef __attribute__((ext_vector_type(2))) float f32x2;

#define NSF 128
#define BN_EPS 1e-3f
#define NR 4            // src ranges per node
#define SCK 2048        // elements per scan block

// ---------------- CSR build: 1 atomic per edge ----------------

__global__ void passA_kernel(const int* __restrict__ ei, int* __restrict__ fill,
                             int* __restrict__ loc, int E, int n, int rsize) {
    int idx = blockIdx.x * blockDim.x + threadIdx.x;
    if (idx < E) {
        int r = ei[idx];
        int c = ei[E + idx];
        int slot = c * NR + r / rsize;
        loc[idx] = atomicAdd(&fill[slot], 1);
    } else if (idx < E + n) {
        int i = idx - E;
        int slot = i * NR + i / rsize;
        loc[idx] = atomicAdd(&fill[slot], 1);
    }
}

// ---- hierarchical exclusive scan of fill -> row_ptr ----

__global__ void scan1_kernel(const int* __restrict__ cnt, int* __restrict__ blksum, int total) {
    __shared__ int red[256];
    int base = blockIdx.x * SCK + threadIdx.x * 8;
    int s = 0;
    #pragma unroll
    for (int i = 0; i < 8; ++i) {
        int idx = base + i;
        if (idx < total) s += cnt[idx];
    }
    red[threadIdx.x] = s;
    __syncthreads();
    for (int off2 = 128; off2 > 0; off2 >>= 1) {
        if (threadIdx.x < off2) red[threadIdx.x] += red[threadIdx.x + off2];
        __syncthreads();
    }
    if (threadIdx.x == 0) blksum[blockIdx.x] = red[0];
}

__global__ void scan2_kernel(int* __restrict__ blksum, int* __restrict__ row_ptr,
                             int nblk, int total) {
    __shared__ int part[256];
    int tid = threadIdx.x;
    int v = (tid < nblk) ? blksum[tid] : 0;
    part[tid] = v;
    __syncthreads();
    for (int off2 = 1; off2 < 256; off2 <<= 1) {
        int t = (tid >= off2) ? part[tid - off2] : 0;
        __syncthreads();
        part[tid] += t;
        __syncthreads();
    }
    if (tid < nblk) blksum[tid] = part[tid] - v;
    if (tid == 255) row_ptr[total] = part[255];
}

__global__ void scan3_kernel(const int* __restrict__ cnt, const int* __restrict__ blkoff,
                             int* __restrict__ row_ptr, int total) {
    __shared__ int part[256];
    int tid = threadIdx.x;
    int base = blockIdx.x * SCK + tid * 8;
    int loc[8]; int s = 0;
    #pragma unroll
    for (int i = 0; i < 8; ++i) {
        int idx = base + i;
        loc[i] = (idx < total) ? cnt[idx] : 0;
        s += loc[i];
    }
    part[tid] = s;
    __syncthreads();
    for (int off2 = 1; off2 < 256; off2 <<= 1) {
        int t = (tid >= off2) ? part[tid - off2] : 0;
        __syncthreads();
        part[tid] += t;
        __syncthreads();
    }
    int run = blkoff[blockIdx.x] + part[tid] - s;
    #pragma unroll
    for (int i = 0; i < 8; ++i) {
        int idx = base + i;
        if (idx < total) { row_ptr[idx] = run; run += loc[i]; }
    }
}

// passB: scatter without atomics; packed edge record {src, w_bits}
__global__ void passB_kernel(const int* __restrict__ ei, const float* __restrict__ ea,
                             const int* __restrict__ row_ptr, const int* __restrict__ loc,
                             int2* __restrict__ e8, int* __restrict__ csr_col,
                             int E, int n, int rsize) {
    int idx = blockIdx.x * blockDim.x + threadIdx.x;
    if (idx < E) {
        int r = ei[idx];
        int c = ei[E + idx];
        int slot = c * NR + r / rsize;
        int p = row_ptr[slot] + loc[idx];
        int2 rec; rec.x = r; rec.y = __float_as_int(ea[idx]);
        e8[p] = rec;
        csr_col[p] = c;
    } else if (idx < E + n) {
        int i = idx - E;
        int slot = i * NR + i / rsize;
        int p = row_ptr[slot] + loc[idx];
        int2 rec; rec.x = i; rec.y = __float_as_int(1.0f);
        e8[p] = rec;
        csr_col[p] = i;
    }
}

__global__ void degdinv_kernel(const int* __restrict__ row_ptr, const int2* __restrict__ e8,
                               float* __restrict__ dinv, int n) {
    int node = blockIdx.x * blockDim.x + threadIdx.x;
    if (node < n) {
        int s = row_ptr[node * NR], e = row_ptr[(node + 1) * NR];
        float d = 0.0f;
        for (int j = s; j < e; ++j) d += __int_as_float(e8[j].y);
        dinv[node] = (d > 0.0f) ? rsqrtf(d) : 0.0f;
    }
}

__global__ void normw_kernel(const float* __restrict__ dinv, const int* __restrict__ csr_col,
                             int2* __restrict__ e8, int EN) {
    int p = blockIdx.x * blockDim.x + threadIdx.x;
    if (p < EN) {
        int2 rec = e8[p];
        float w = dinv[rec.x] * __int_as_float(rec.y) * dinv[csr_col[p]];
        ((int*)e8)[2 * p + 1] = __float_as_int(w);
    }
}

// ---------------- output-type helpers (HW fp8 cvt) ----------------

__device__ inline void store_val(bf16* C, size_t idx, float a) {
    C[idx] = __float2bfloat16(a);
}
__device__ inline void store_val(fp8* C, size_t idx, float a) {
    int packed = __builtin_amdgcn_cvt_pk_fp8_f32(a, a, 0, false);
    C[idx] = (fp8)(packed & 0xff);
}

// ---------------- fused prep: zero fill[] + x->fp8 + all W->Wt(bf16), one launch ----------------
__global__ void prep_kernel(int* __restrict__ fill, int total,
                            const float* __restrict__ x, fp8* __restrict__ xq, int xcnt,
                            const float* __restrict__ W0, const float* __restrict__ W1,
                            const float* __restrict__ W2, const float* __restrict__ W3,
                            const float* __restrict__ W4,
                            bf16* __restrict__ wtbuf, int wtelems) {
    int idx = blockIdx.x * blockDim.x + threadIdx.x;
    if (idx < total) { fill[idx] = 0; return; }
    idx -= total;
    if (idx < xcnt) {
        store_val(xq, idx, x[idx]);
        return;
    }
    int widx = idx - xcnt;
    if (widx >= wtelems) return;
    // layer boundaries (cumulative K*N): 32768, 163840, 294912, 327680, 344064
    const float* W; int K, off;
    if (widx < 32768)       { W = W0; K = 128; off = 0; }
    else if (widx < 163840) { W = W1; K = 256; off = 32768; }
    else if (widx < 294912) { W = W2; K = 512; off = 163840; }
    else if (widx < 327680) { W = W3; K = 256; off = 294912; }
    else                    { W = W4; K = 128; off = 327680; }
    int N2;
    if (widx < 32768) N2 = 256; else if (widx < 163840) N2 = 512;
    else if (widx < 294912) N2 = 256; else N2 = 128;
    int l = widx - off;
    int nn = l / K, kk = l % K;
    wtbuf[widx] = __float2bfloat16(W[(size_t)kk * N2 + nn]);
}

// ---------------- direct global->LDS 16B staging ----------------

__device__ inline void gl_lds16(const bf16* g, bf16* l) {
    __builtin_amdgcn_global_load_lds(
        (const __attribute__((address_space(1))) void*)g,
        (__attribute__((address_space(3))) void*)l,
        16, 0, 0);
}

// ---------------- MFMA GEMM (64x128 tile, BK=64 dual-stage): C = A @ Wt^T ----------------
// mode 0: raw store; mode 1: sigmoid(BN(acc+bias))

template <typename OT>
__global__ __launch_bounds__(256) void mfma_gemm_kernel(
    const bf16* __restrict__ A, const bf16* __restrict__ Wt,
    OT* __restrict__ C, int M, int K, int N, int mode,
    const float* __restrict__ bias, const float* __restrict__ g,
    const float* __restrict__ be, const float* __restrict__ m,
    const float* __restrict__ v) {
    __shared__ bf16 As[2][64][32];
    __shared__ bf16 Bs[2][128][32];
    int m0 = blockIdx.x * 64;
    int n0 = blockIdx.y * 128;
    int tid = threadIdx.x;
    int wave = tid >> 6, lane = tid & 63;
    int lrow = lane & 15, quad = lane >> 4;

    f32x4 acc[4][2] = {};   // [m-tile][n-tile]

    int srow = lane >> 2;
    int sseg = lane & 3;
    int am = wave * 16 + srow;
    int bn = wave * 32 + srow;
    bool aok = (m0 + am) < M;

    for (int k0 = 0; k0 < K; k0 += 64) {
        if (aok) {
            gl_lds16(A + (size_t)(m0 + am) * K + k0 + sseg * 8,      &As[0][am][sseg * 8]);
            gl_lds16(A + (size_t)(m0 + am) * K + k0 + 32 + sseg * 8, &As[1][am][sseg * 8]);
        }
        gl_lds16(Wt + (size_t)(n0 + bn) * K + k0 + sseg * 8,           &Bs[0][bn][sseg * 8]);
        gl_lds16(Wt + (size_t)(n0 + bn) * K + k0 + 32 + sseg * 8,      &Bs[1][bn][sseg * 8]);
        gl_lds16(Wt + (size_t)(n0 + bn + 16) * K + k0 + sseg * 8,      &Bs[0][bn + 16][sseg * 8]);
        gl_lds16(Wt + (size_t)(n0 + bn + 16) * K + k0 + 32 + sseg * 8, &Bs[1][bn + 16][sseg * 8]);
        __syncthreads();

        #pragma unroll
        for (int ks = 0; ks < 2; ++ks) {
            short8 afrag[4], bfrag[2];
            #pragma unroll
            for (int mt = 0; mt < 4; ++mt)
                afrag[mt] = *(const short8*)(&As[ks][mt * 16 + lrow][quad * 8]);
            #pragma unroll
            for (int nt = 0; nt < 2; ++nt)
                bfrag[nt] = *(const short8*)(&Bs[ks][wave * 32 + nt * 16 + lrow][quad * 8]);
            #pragma unroll
            for (int mt = 0; mt < 4; ++mt)
                #pragma unroll
                for (int nt = 0; nt < 2; ++nt)
                    acc[mt][nt] = __builtin_amdgcn_mfma_f32_16x16x32_bf16(
                        afrag[mt], bfrag[nt], acc[mt][nt], 0, 0, 0);
        }
        __syncthreads();
    }
    // C/D: col = lane&15, row = quad*4 + reg
    #pragma unroll
    for (int nt = 0; nt < 2; ++nt) {
        int gn = n0 + wave * 32 + nt * 16 + lrow;
        float bsc = 0.0f, scale = 1.0f, mean = 0.0f, beta = 0.0f;
        if (mode == 1) {
            bsc = bias[gn];
            scale = g[gn] * rsqrtf(v[gn] + BN_EPS);
            mean = m[gn];
            beta = be[gn];
        }
        #pragma unroll
        for (int mt = 0; mt < 4; ++mt) {
            #pragma unroll
            for (int rr = 0; rr < 4; ++rr) {
                int gm = m0 + mt * 16 + quad * 4 + rr;
                if (gm < M) {
                    float a = acc[mt][nt][rr];
                    if (mode == 1) {
                        a = (a + bsc - mean) * scale + beta;
                        a = 1.0f / (1.0f + __expf(-a));
                    }
                    store_val(C, (size_t)gm * N + gn, a);
                }
            }
        }
    }
}

// ---------------- fp8 aggregation: 4-wave-per-node split (round 26) ----------------
// Each block owns ONE node; wave w gathers source-bucket w (~deg/4 edges), partials
// merged via LDS. Tests the per-wave serialized-latency model: per-wave chain drops
// from {record L + 26-gather drain} to {record L + ~7-gather fill}, wave count x4.

template <int VEC> struct F8Vec;
template <> struct F8Vec<2> { typedef unsigned short T; };
template <> struct F8Vec<4> { typedef unsigned int T; };

__device__ inline void fma_f8(unsigned short q, float w, float* acc) {
    f32x2 lo = __builtin_amdgcn_cvt_pk_f32_fp8((unsigned int)q, false);
    acc[0] += w * lo.x;
    acc[1] += w * lo.y;
}
__device__ inline void fma_f8(unsigned int q, float w, float* acc) {
    f32x2 lo = __builtin_amdgcn_cvt_pk_f32_fp8(q, false);
    f32x2 hi = __builtin_amdgcn_cvt_pk_f32_fp8(q, true);
    acc[0] += w * lo.x;
    acc[1] += w * lo.y;
    acc[2] += w * hi.x;
    acc[3] += w * hi.y;
}

template <int VEC>
__global__ __launch_bounds__(256) void agg_fp8_kernel(
    const fp8* __restrict__ hw,
    const int* __restrict__ row_ptr, const int2* __restrict__ e8,
    const float* __restrict__ bias,
    const float* __restrict__ g, const float* __restrict__ be,
    const float* __restrict__ m, const float* __restrict__ v,
    bf16* __restrict__ out, int n, int mode) {
    typedef typename F8Vec<VEC>::T T;
    const int dfeat = VEC * 64;
    __shared__ int2 recs[4][64];
    __shared__ float red[4][VEC * 64];
    int wave = threadIdx.x >> 6;
    int lane = threadIdx.x & 63;
    int node = blockIdx.x;
    // wave w handles bucket w of this node
    int s = row_ptr[node * NR + wave], e = row_ptr[node * NR + wave + 1];
    float acc[VEC];
    #pragma unroll
    for (int i = 0; i < VEC; ++i) acc[i] = 0.0f;
    const unsigned int base = (unsigned int)lane * VEC;

#define LOADG(Q, WV, J0)                                                     \
    _Pragma("unroll")                                                        \
    for (int u = 0; u < 8; ++u) {                                            \
        int2 rec = recs[wave][(J0) + u];                                     \
        WV[u] = __int_as_float(rec.y);                                       \
        Q[u] = *(const T*)(hw + ((unsigned int)rec.x * dfeat + base));       \
    }
#define CONSUME(Q, WV)                                                       \
    _Pragma("unroll")                                                        \
    for (int u = 0; u < 8; ++u) fma_f8(Q[u], WV[u], acc);

    for (int cs = s; cs < e; cs += 64) {
        int cnt = e - cs; if (cnt > 64) cnt = 64;
        // cooperative coalesced record load; pad with {src=0, w=0}
        int2 r0; r0.x = 0; r0.y = 0;
        if (lane < cnt) r0 = e8[cs + lane];
        recs[wave][lane] = r0;
        // wave-local fence: only this wave touches recs[wave][*]
        asm volatile("s_waitcnt vmcnt(0) lgkmcnt(0)" ::: "memory");

        int npad = (cnt + 15) & ~15;   // >= 16
        T qA[8], qB[8];
        float wA[8], wB[8];
        LOADG(qA, wA, 0)
        LOADG(qB, wB, 8)
        for (int j0 = 16; j0 < npad; j0 += 16) {
            CONSUME(qA, wA)
            LOADG(qA, wA, j0)
            CONSUME(qB, wB)
            LOADG(qB, wB, j0 + 8)
        }
        CONSUME(qA, wA)
        CONSUME(qB, wB)
    }
#undef LOADG
#undef CONSUME

    #pragma unroll
    for (int i = 0; i < VEC; ++i) red[wave][base + i] = acc[i];
    __syncthreads();

    // cross-wave merge + epilogue: thread f owns feature f
    int f = threadIdx.x;
    if (f < dfeat) {
        float a = red[0][f] + red[1][f] + red[2][f] + red[3][f];
        if (mode != 0) {
            a += bias[f];
            if (mode == 1) {
                float scale = g[f] * rsqrtf(v[f] + BN_EPS);
                a = (a - m[f]) * scale + be[f];
            }
            a = 1.0f / (1.0f + __expf(-a));
        }
        out[(size_t)node * dfeat + f] = __float2bfloat16(a);
    }
}

// ---------------- final h^T h via MFMA ----------------
#define TPAD 8

__global__ __launch_bounds__(256) void htht_mfma_kernel(
    const bf16* __restrict__ h, float* __restrict__ partial, int n) {
    __shared__ bf16 hsT[128][32 + TPAD];
    int b = blockIdx.x;
    int tid = threadIdx.x;
    int wave = tid >> 6, lane = tid & 63;
    int lrow = lane & 15, quad = lane >> 4;

    f32x4 acc[2][8] = {};

    int kk = tid >> 3;
    int seg = tid & 7;

    for (int kt = 0; kt < 8; ++kt) {
        int k0 = b * 256 + kt * 32;
        #pragma unroll
        for (int s2 = 0; s2 < 2; ++s2) {
            int fs = (seg + s2 * 8) * 8;
            int gk = k0 + kk;
            uint4 q; q.x = q.y = q.z = q.w = 0u;
            if (gk < n) q = *(const uint4*)(h + (size_t)gk * 128 + fs);
            const unsigned short* u = (const unsigned short*)&q;
            #pragma unroll
            for (int i = 0; i < 8; ++i)
                *((unsigned short*)&hsT[fs + i][kk]) = u[i];
        }
        __syncthreads();
        short8 af0 = *(const short8*)(&hsT[wave * 32 + lrow][quad * 8]);
        short8 af1 = *(const short8*)(&hsT[wave * 32 + 16 + lrow][quad * 8]);
        #pragma unroll
        for (int t = 0; t < 8; ++t) {
            short8 bfrag = *(const short8*)(&hsT[t * 16 + lrow][quad * 8]);
            acc[0][t] = __builtin_amdgcn_mfma_f32_16x16x32_bf16(af0, bfrag, acc[0][t], 0, 0, 0);
            acc[1][t] = __builtin_amdgcn_mfma_f32_16x16x32_bf16(af1, bfrag, acc[1][t], 0, 0, 0);
        }
        __syncthreads();
    }
    float* p = partial + (size_t)b * 16384;
    #pragma unroll
    for (int a_ = 0; a_ < 2; ++a_) {
        #pragma unroll
        for (int t = 0; t < 8; ++t) {
            #pragma unroll
            for (int rr = 0; rr < 4; ++rr) {
                int gm = wave * 32 + a_ * 16 + quad * 4 + rr;
                int gn = t * 16 + lrow;
                p[gm * 128 + gn] = acc[a_][t][rr];
            }
        }
    }
}

__global__ void reduce_kernel(const float* __restrict__ partial, float* __restrict__ out, int nchunks) {
    int idx = blockIdx.x * blockDim.x + threadIdx.x;
    float s = 0.0f;
    for (int c = 0; c < nchunks; ++c) s += partial[(size_t)c * 16384 + idx];
    int i = idx / 128, j = idx % 128;
    out[idx] = (i == j) ? 0.0f : s;
}

// ---------------- launch ----------------
extern "C" void kernel_launch(void* const* d_in, const int* in_sizes, int n_in,
                              void* d_out, int out_size, void* d_ws, size_t ws_size,
                              hipStream_t stream) {
    const float* x  = (const float*)d_in[0];
    const int*   ei = (const int*)d_in[1];
    const float* ea = (const float*)d_in[2];
    const float* W[5];  const float* bvec[5];
    for (int l = 0; l < 5; ++l) { W[l] = (const float*)d_in[3 + 2 * l]; bvec[l] = (const float*)d_in[4 + 2 * l]; }
    const float* g[4]; const float* be[4]; const float* mm[4]; const float* vv[4];
    for (int l = 0; l < 4; ++l) {
        g[l]  = (const float*)d_in[13 + 4 * l];
        be[l] = (const float*)d_in[14 + 4 * l];
        mm[l] = (const float*)d_in[15 + 4 * l];
        vv[l] = (const float*)d_in[16 + 4 * l];
    }
    const int n = in_sizes[0] / NSF;        // 20000
    const int E = in_sizes[1] / 2;          // 500000
    const int EN = E + n;
    const int rsize = (n + NR - 1) / NR;
    const int total = n * NR;
    const int nscan = (total + SCK - 1) / SCK;
    const int dims[6] = {128, 256, 512, 256, 128, 128};
    const int wtoff[5] = {0, 32768, 163840, 294912, 327680};
    const int wtelems = 344064;

    // workspace layout (256B aligned); ~69 MB (identical to known-good round-1 layout)
    auto align = [](size_t o) { return (o + 255) & ~(size_t)255; };
    size_t off = 0;
    float* dinv    = (float*)((char*)d_ws + off); off = align(off + (size_t)n * 4);
    int*   fill    = (int*)  ((char*)d_ws + off); off = align(off + (size_t)total * 4);
    int*   row_ptr = (int*)  ((char*)d_ws + off); off = align(off + ((size_t)total + 1) * 4);
    int*   blksum  = (int*)  ((char*)d_ws + off); off = align(off + (size_t)256 * 4);
    int*   locb    = (int*)  ((char*)d_ws + off); off = align(off + (size_t)EN * 4);
    int2*  e8      = (int2*) ((char*)d_ws + off); off = align(off + (size_t)EN * 8);
    int*   csr_col = (int*)  ((char*)d_ws + off); off = align(off + (size_t)EN * 4);
    bf16*  wtbuf   = (bf16*) ((char*)d_ws + off); off = align(off + (size_t)wtelems * 2);
    fp8*   xq      = (fp8*)  ((char*)d_ws + off); off = align(off + (size_t)n * 128);
    bf16*  hbuf    = (bf16*) ((char*)d_ws + off); off = align(off + (size_t)n * 512 * 2);
    bf16*  abuf    = (bf16*) ((char*)d_ws + off); off = align(off + (size_t)n * 512 * 2);
    fp8*   f8buf   = (fp8*)  ((char*)d_ws + off); off = align(off + (size_t)n * 256);
    const int KCH = (20000 + 255) / 256;    // 79
    float* partial = (float*)((char*)d_ws + off); off = align(off + (size_t)KCH * 16384 * 4);

    // fused prep: zero fill + x->fp8 + W->Wt (one launch, independent of edges)
    {
        int xcnt = n * 128;
        int items = total + xcnt + wtelems;
        prep_kernel<<<(items + 255) / 256, 256, 0, stream>>>(fill, total, x, xq, xcnt,
            W[0], W[1], W[2], W[3], W[4], wtbuf, wtelems);
    }

    // CSR build (1 atomic/edge, packed edge records)
    passA_kernel<<<(EN + 255) / 256, 256, 0, stream>>>(ei, fill, locb, E, n, rsize);
    scan1_kernel<<<nscan, 256, 0, stream>>>(fill, blksum, total);
    scan2_kernel<<<1, 256, 0, stream>>>(blksum, row_ptr, nscan, total);
    scan3_kernel<<<nscan, 256, 0, stream>>>(fill, blksum, row_ptr, total);
    passB_kernel<<<(EN + 255) / 256, 256, 0, stream>>>(ei, ea, row_ptr, locb,
                                                       e8, csr_col, E, n, rsize);
    degdinv_kernel<<<(n + 255) / 256, 256, 0, stream>>>(row_ptr, e8, dinv, n);
    normw_kernel<<<(EN + 255) / 256, 256, 0, stream>>>(dinv, csr_col, e8, EN);

    auto gemm_bf16 = [&](const bf16* A, int l, bf16* C, int mode) {
        int K = dims[l], N = dims[l + 1];
        dim3 gg((n + 63) / 64, N / 128);
        int bi = (l < 4) ? l : 0;
        mfma_gemm_kernel<bf16><<<gg, 256, 0, stream>>>(A, wtbuf + wtoff[l], C, n, K, N, mode,
                                                       bvec[l], g[bi], be[bi], mm[bi], vv[bi]);
    };
    auto gemm_fp8 = [&](const bf16* A, int l, fp8* C, int mode) {
        int K = dims[l], N = dims[l + 1];
        dim3 gg((n + 63) / 64, N / 128);
        int bi = (l < 4) ? l : 0;
        mfma_gemm_kernel<fp8><<<gg, 256, 0, stream>>>(A, wtbuf + wtoff[l], C, n, K, N, mode,
                                                      bvec[l], g[bi], be[bi], mm[bi], vv[bi]);
    };

    // L1 (128->256): agg-first fp8 128 (xq), GEMM1 fused act -> fp8 h1
    agg_fp8_kernel<2><<<n, 256, 0, stream>>>(xq, row_ptr, e8,
        bvec[0], bvec[0], bvec[0], bvec[0], bvec[0], abuf, n, 0);
    gemm_fp8(abuf, 0, f8buf, 1);
    // L2 (256->512): agg-first fp8 256 (h1) -> bf16, GEMM2 fused act -> bf16 h2 (512)
    agg_fp8_kernel<4><<<n, 256, 0, stream>>>(f8buf, row_ptr, e8,
        bvec[1], bvec[1], bvec[1], bvec[1], bvec[1], abuf, n, 0);
    gemm_bf16(abuf, 1, hbuf, 1);
    // L3 (512->256): GEMM3 raw -> fp8 hw3, agg-last fp8 256 + bias+BN+sigmoid -> bf16 h3
    gemm_fp8(hbuf, 2, f8buf, 0);
    agg_fp8_kernel<4><<<n, 256, 0, stream>>>(f8buf, row_ptr, e8,
        bvec[2], g[2], be[2], mm[2], vv[2], abuf, n, 1);
    // L4 (256->128): GEMM4 raw -> fp8 hw4, agg-last fp8 128 + bias+BN+sigmoid -> bf16 h4
    gemm_fp8(abuf, 3, f8buf, 0);
    agg_fp8_kernel<2><<<n, 256, 0, stream>>>(f8buf, row_ptr, e8,
        bvec[3], g[3], be[3], mm[3], vv[3], hbuf, n, 1);
    // L5 (128->128): GEMM5 raw -> fp8 hw5, agg-last fp8 128 + bias+sigmoid -> bf16 h5
    gemm_fp8(hbuf, 4, f8buf, 0);
    agg_fp8_kernel<2><<<n, 256, 0, stream>>>(f8buf, row_ptr, e8,
        bvec[4], bvec[4], bvec[4], bvec[4], bvec[4], abuf, n, 2);

    // final h^T h with zeroed diagonal (MFMA)
    htht_mfma_kernel<<<KCH, 256, 0, stream>>>(abuf, partial, n);
    reduce_kernel<<<16384 / 256, 256, 0, stream>>>(partial, (float*)d_out, KCH);
}

// Round 11
// 385.296 us; speedup vs baseline: 1.9305x; 1.1063x over previous
//
#include <hip/hip_runtime.h>
#include <hip/hip_bf16.h>
#include <hip/hip_fp8.h>
#include <cstdint>
#include <cstddef>
#include <cstring>

typedef __hip_bfloat16 bf16;
typedef unsigned char fp8;                                  // e4m3 storage
typedef __attribute__((ext_vector_type(8))) short short8;   // 8 bf16 (MFMA A/B frag)
typedef __attribute__((ext_vector_type(4))) float f32x4;    // MFMA C/D frag
typedef __attribute__((ext_vector_type(2))) float f32x2;

#define NSF 128
#define BN_EPS 1e-3f
#define NR 4            // src ranges per node
#define SCK 2048        // elements per scan block

// ---------------- CSR build: 1 atomic per edge ----------------

__global__ void passA_kernel(const int* __restrict__ ei, int* __restrict__ fill,
                             int* __restrict__ loc, int E, int n, int rsize) {
    int idx = blockIdx.x * blockDim.x + threadIdx.x;
    if (idx < E) {
        int r = ei[idx];
        int c = ei[E + idx];
        int slot = c * NR + r / rsize;
        loc[idx] = atomicAdd(&fill[slot], 1);
    } else if (idx < E + n) {
        int i = idx - E;
        int slot = i * NR + i / rsize;
        loc[idx] = atomicAdd(&fill[slot], 1);
    }
}

// ---- hierarchical exclusive scan of fill -> row_ptr ----

__global__ void scan1_kernel(const int* __restrict__ cnt, int* __restrict__ blksum, int total) {
    __shared__ int red[256];
    int base = blockIdx.x * SCK + threadIdx.x * 8;
    int s = 0;
    #pragma unroll
    for (int i = 0; i < 8; ++i) {
        int idx = base + i;
        if (idx < total) s += cnt[idx];
    }
    red[threadIdx.x] = s;
    __syncthreads();
    for (int off2 = 128; off2 > 0; off2 >>= 1) {
        if (threadIdx.x < off2) red[threadIdx.x] += red[threadIdx.x + off2];
        __syncthreads();
    }
    if (threadIdx.x == 0) blksum[blockIdx.x] = red[0];
}

__global__ void scan2_kernel(int* __restrict__ blksum, int* __restrict__ row_ptr,
                             int nblk, int total) {
    __shared__ int part[256];
    int tid = threadIdx.x;
    int v = (tid < nblk) ? blksum[tid] : 0;
    part[tid] = v;
    __syncthreads();
    for (int off2 = 1; off2 < 256; off2 <<= 1) {
        int t = (tid >= off2) ? part[tid - off2] : 0;
        __syncthreads();
        part[tid] += t;
        __syncthreads();
    }
    if (tid < nblk) blksum[tid] = part[tid] - v;
    if (tid == 255) row_ptr[total] = part[255];
}

__global__ void scan3_kernel(const int* __restrict__ cnt, const int* __restrict__ blkoff,
                             int* __restrict__ row_ptr, int total) {
    __shared__ int part[256];
    int tid = threadIdx.x;
    int base = blockIdx.x * SCK + tid * 8;
    int loc[8]; int s = 0;
    #pragma unroll
    for (int i = 0; i < 8; ++i) {
        int idx = base + i;
        loc[i] = (idx < total) ? cnt[idx] : 0;
        s += loc[i];
    }
    part[tid] = s;
    __syncthreads();
    for (int off2 = 1; off2 < 256; off2 <<= 1) {
        int t = (tid >= off2) ? part[tid - off2] : 0;
        __syncthreads();
        part[tid] += t;
        __syncthreads();
    }
    int run = blkoff[blockIdx.x] + part[tid] - s;
    #pragma unroll
    for (int i = 0; i < 8; ++i) {
        int idx = base + i;
        if (idx < total) { row_ptr[idx] = run; run += loc[i]; }
    }
}

// passB: scatter without atomics; packed edge record {src, w_bits}
__global__ void passB_kernel(const int* __restrict__ ei, const float* __restrict__ ea,
                             const int* __restrict__ row_ptr, const int* __restrict__ loc,
                             int2* __restrict__ e8, int* __restrict__ csr_col,
                             int E, int n, int rsize) {
    int idx = blockIdx.x * blockDim.x + threadIdx.x;
    if (idx < E) {
        int r = ei[idx];
        int c = ei[E + idx];
        int slot = c * NR + r / rsize;
        int p = row_ptr[slot] + loc[idx];
        int2 rec; rec.x = r; rec.y = __float_as_int(ea[idx]);
        e8[p] = rec;
        csr_col[p] = c;
    } else if (idx < E + n) {
        int i = idx - E;
        int slot = i * NR + i / rsize;
        int p = row_ptr[slot] + loc[idx];
        int2 rec; rec.x = i; rec.y = __float_as_int(1.0f);
        e8[p] = rec;
        csr_col[p] = i;
    }
}

__global__ void degdinv_kernel(const int* __restrict__ row_ptr, const int2* __restrict__ e8,
                               float* __restrict__ dinv, int n) {
    int node = blockIdx.x * blockDim.x + threadIdx.x;
    if (node < n) {
        int s = row_ptr[node * NR], e = row_ptr[(node + 1) * NR];
        float d = 0.0f;
        for (int j = s; j < e; ++j) d += __int_as_float(e8[j].y);
        dinv[node] = (d > 0.0f) ? rsqrtf(d) : 0.0f;
    }
}

__global__ void normw_kernel(const float* __restrict__ dinv, const int* __restrict__ csr_col,
                             int2* __restrict__ e8, int EN) {
    int p = blockIdx.x * blockDim.x + threadIdx.x;
    if (p < EN) {
        int2 rec = e8[p];
        float w = dinv[rec.x] * __int_as_float(rec.y) * dinv[csr_col[p]];
        ((int*)e8)[2 * p + 1] = __float_as_int(w);
    }
}

// ---------------- output-type helpers (HW fp8 cvt) ----------------

__device__ inline void store_val(bf16* C, size_t idx, float a) {
    C[idx] = __float2bfloat16(a);
}
__device__ inline void store_val(fp8* C, size_t idx, float a) {
    int packed = __builtin_amdgcn_cvt_pk_fp8_f32(a, a, 0, false);
    C[idx] = (fp8)(packed & 0xff);
}

// ---------------- fused prep: zero fill[] + x->fp8 + all W->Wt(bf16), one launch ----------------
__global__ void prep_kernel(int* __restrict__ fill, int total,
                            const float* __restrict__ x, fp8* __restrict__ xq, int xcnt,
                            const float* __restrict__ W0, const float* __restrict__ W1,
                            const float* __restrict__ W2, const float* __restrict__ W3,
                            const float* __restrict__ W4,
                            bf16* __restrict__ wtbuf, int wtelems) {
    int idx = blockIdx.x * blockDim.x + threadIdx.x;
    if (idx < total) { fill[idx] = 0; return; }
    idx -= total;
    if (idx < xcnt) {
        store_val(xq, idx, x[idx]);
        return;
    }
    int widx = idx - xcnt;
    if (widx >= wtelems) return;
    // layer boundaries (cumulative K*N): 32768, 163840, 294912, 327680, 344064
    const float* W; int K, off;
    if (widx < 32768)       { W = W0; K = 128; off = 0; }
    else if (widx < 163840) { W = W1; K = 256; off = 32768; }
    else if (widx < 294912) { W = W2; K = 512; off = 163840; }
    else if (widx < 327680) { W = W3; K = 256; off = 294912; }
    else                    { W = W4; K = 128; off = 327680; }
    int N2;
    if (widx < 32768) N2 = 256; else if (widx < 163840) N2 = 512;
    else if (widx < 294912) N2 = 256; else N2 = 128;
    int l = widx - off;
    int nn = l / K, kk = l % K;
    wtbuf[widx] = __float2bfloat16(W[(size_t)kk * N2 + nn]);
}

// ---------------- direct global->LDS 16B staging ----------------

__device__ inline void gl_lds16(const bf16* g, bf16* l) {
    __builtin_amdgcn_global_load_lds(
        (const __attribute__((address_space(1))) void*)g,
        (__attribute__((address_space(3))) void*)l,
        16, 0, 0);
}

// ---------------- MFMA GEMM (64x128 tile, BK=64 dual-stage): C = A @ Wt^T ----------------
// mode 0: raw store; mode 1: sigmoid(BN(acc+bias))

template <typename OT>
__global__ __launch_bounds__(256) void mfma_gemm_kernel(
    const bf16* __restrict__ A, const bf16* __restrict__ Wt,
    OT* __restrict__ C, int M, int K, int N, int mode,
    const float* __restrict__ bias, const float* __restrict__ g,
    const float* __restrict__ be, const float* __restrict__ m,
    const float* __restrict__ v) {
    __shared__ bf16 As[2][64][32];
    __shared__ bf16 Bs[2][128][32];
    int m0 = blockIdx.x * 64;
    int n0 = blockIdx.y * 128;
    int tid = threadIdx.x;
    int wave = tid >> 6, lane = tid & 63;
    int lrow = lane & 15, quad = lane >> 4;

    f32x4 acc[4][2] = {};   // [m-tile][n-tile]

    int srow = lane >> 2;
    int sseg = lane & 3;
    int am = wave * 16 + srow;
    int bn = wave * 32 + srow;
    bool aok = (m0 + am) < M;

    for (int k0 = 0; k0 < K; k0 += 64) {
        if (aok) {
            gl_lds16(A + (size_t)(m0 + am) * K + k0 + sseg * 8,      &As[0][am][sseg * 8]);
            gl_lds16(A + (size_t)(m0 + am) * K + k0 + 32 + sseg * 8, &As[1][am][sseg * 8]);
        }
        gl_lds16(Wt + (size_t)(n0 + bn) * K + k0 + sseg * 8,           &Bs[0][bn][sseg * 8]);
        gl_lds16(Wt + (size_t)(n0 + bn) * K + k0 + 32 + sseg * 8,      &Bs[1][bn][sseg * 8]);
        gl_lds16(Wt + (size_t)(n0 + bn + 16) * K + k0 + sseg * 8,      &Bs[0][bn + 16][sseg * 8]);
        gl_lds16(Wt + (size_t)(n0 + bn + 16) * K + k0 + 32 + sseg * 8, &Bs[1][bn + 16][sseg * 8]);
        __syncthreads();

        #pragma unroll
        for (int ks = 0; ks < 2; ++ks) {
            short8 afrag[4], bfrag[2];
            #pragma unroll
            for (int mt = 0; mt < 4; ++mt)
                afrag[mt] = *(const short8*)(&As[ks][mt * 16 + lrow][quad * 8]);
            #pragma unroll
            for (int nt = 0; nt < 2; ++nt)
                bfrag[nt] = *(const short8*)(&Bs[ks][wave * 32 + nt * 16 + lrow][quad * 8]);
            #pragma unroll
            for (int mt = 0; mt < 4; ++mt)
                #pragma unroll
                for (int nt = 0; nt < 2; ++nt)
                    acc[mt][nt] = __builtin_amdgcn_mfma_f32_16x16x32_bf16(
                        afrag[mt], bfrag[nt], acc[mt][nt], 0, 0, 0);
        }
        __syncthreads();
    }
    // C/D: col = lane&15, row = quad*4 + reg
    #pragma unroll
    for (int nt = 0; nt < 2; ++nt) {
        int gn = n0 + wave * 32 + nt * 16 + lrow;
        float bsc = 0.0f, scale = 1.0f, mean = 0.0f, beta = 0.0f;
        if (mode == 1) {
            bsc = bias[gn];
            scale = g[gn] * rsqrtf(v[gn] + BN_EPS);
            mean = m[gn];
            beta = be[gn];
        }
        #pragma unroll
        for (int mt = 0; mt < 4; ++mt) {
            #pragma unroll
            for (int rr = 0; rr < 4; ++rr) {
                int gm = m0 + mt * 16 + quad * 4 + rr;
                if (gm < M) {
                    float a = acc[mt][nt][rr];
                    if (mode == 1) {
                        a = (a + bsc - mean) * scale + beta;
                        a = 1.0f / (1.0f + __expf(-a));
                    }
                    store_val(C, (size_t)gm * N + gn, a);
                }
            }
        }
    }
}

// ---------------- fp8 aggregation: scalar-base gathers (round 27) ----------------
// Round-8 structure (4 nodes/block, A/B pipelined chunks) with one key change: the
// gather row base rec.x is wave-uniform (broadcast from LDS) but lived in a VGPR, so
// the compiler emitted 64-lane arbitrary-address loads and the TA paid full
// address-coalescing cost per instruction (~50cy — explains VEC2==VEC4 duration,
// ILP nulls, and the multi-row-packing disaster). readfirstlane moves the base to
// an SGPR -> saddr-form global_load (scalar base + lane offset), the cheap TA path.

template <int VEC> struct F8Vec;
template <> struct F8Vec<2> { typedef unsigned short T; };
template <> struct F8Vec<4> { typedef unsigned int T; };

__device__ inline void fma_f8(unsigned short q, float w, float* acc) {
    f32x2 lo = __builtin_amdgcn_cvt_pk_f32_fp8((unsigned int)q, false);
    acc[0] += w * lo.x;
    acc[1] += w * lo.y;
}
__device__ inline void fma_f8(unsigned int q, float w, float* acc) {
    f32x2 lo = __builtin_amdgcn_cvt_pk_f32_fp8(q, false);
    f32x2 hi = __builtin_amdgcn_cvt_pk_f32_fp8(q, true);
    acc[0] += w * lo.x;
    acc[1] += w * lo.y;
    acc[2] += w * hi.x;
    acc[3] += w * hi.y;
}

template <int VEC>
__global__ __launch_bounds__(256) void agg_fp8_kernel(
    const fp8* __restrict__ hw,
    const int* __restrict__ row_ptr, const int2* __restrict__ e8,
    const float* __restrict__ bias,
    const float* __restrict__ g, const float* __restrict__ be,
    const float* __restrict__ m, const float* __restrict__ v,
    bf16* __restrict__ out, int n, int mode) {
    typedef typename F8Vec<VEC>::T T;
    const int dfeat = VEC * 64;
    __shared__ int2 recs[4][64];
    int wave = threadIdx.x >> 6;
    int lane = threadIdx.x & 63;
    int node = blockIdx.x * 4 + wave;
    if (node >= n) return;
    int s = row_ptr[node * NR], e = row_ptr[(node + 1) * NR];
    float acc[VEC];
    #pragma unroll
    for (int i = 0; i < VEC; ++i) acc[i] = 0.0f;
    const unsigned int base = (unsigned int)lane * VEC;

#define LOADG(Q, WV, J0)                                                     \
    _Pragma("unroll")                                                        \
    for (int u = 0; u < 8; ++u) {                                            \
        int2 rec = recs[wave][(J0) + u];                                     \
        unsigned srcs = (unsigned)__builtin_amdgcn_readfirstlane(rec.x);     \
        WV[u] = __int_as_float(__builtin_amdgcn_readfirstlane(rec.y));       \
        Q[u] = *(const T*)(hw + ((size_t)srcs * dfeat + base));              \
    }
#define CONSUME(Q, WV)                                                       \
    _Pragma("unroll")                                                        \
    for (int u = 0; u < 8; ++u) fma_f8(Q[u], WV[u], acc);

    for (int cs = s; cs < e; cs += 64) {
        int cnt = e - cs; if (cnt > 64) cnt = 64;
        // cooperative coalesced record load; pad with {src=0, w=0}
        int2 r0; r0.x = 0; r0.y = 0;
        if (lane < cnt) r0 = e8[cs + lane];
        recs[wave][lane] = r0;
        // wave-local fence: only this wave touches recs[wave][*]
        asm volatile("s_waitcnt vmcnt(0) lgkmcnt(0)" ::: "memory");

        int npad = (cnt + 15) & ~15;   // >= 16
        T qA[8], qB[8];
        float wA[8], wB[8];
        LOADG(qA, wA, 0)
        LOADG(qB, wB, 8)
        for (int j0 = 16; j0 < npad; j0 += 16) {
            CONSUME(qA, wA)            // waits vmcnt(8): B still in flight
            LOADG(qA, wA, j0)
            CONSUME(qB, wB)
            LOADG(qB, wB, j0 + 8)
        }
        CONSUME(qA, wA)
        CONSUME(qB, wB)
    }
#undef LOADG
#undef CONSUME

    #pragma unroll
    for (int i = 0; i < VEC; ++i) {
        int f = (int)base + i;
        float a = acc[i];
        if (mode != 0) {
            a += bias[f];
            if (mode == 1) {
                float scale = g[f] * rsqrtf(v[f] + BN_EPS);
                a = (a - m[f]) * scale + be[f];
            }
            a = 1.0f / (1.0f + __expf(-a));
        }
        out[(size_t)node * dfeat + f] = __float2bfloat16(a);
    }
}

// ---------------- final h^T h via MFMA ----------------
#define TPAD 8

__global__ __launch_bounds__(256) void htht_mfma_kernel(
    const bf16* __restrict__ h, float* __restrict__ partial, int n) {
    __shared__ bf16 hsT[128][32 + TPAD];
    int b = blockIdx.x;
    int tid = threadIdx.x;
    int wave = tid >> 6, lane = tid & 63;
    int lrow = lane & 15, quad = lane >> 4;

    f32x4 acc[2][8] = {};

    int kk = tid >> 3;
    int seg = tid & 7;

    for (int kt = 0; kt < 8; ++kt) {
        int k0 = b * 256 + kt * 32;
        #pragma unroll
        for (int s2 = 0; s2 < 2; ++s2) {
            int fs = (seg + s2 * 8) * 8;
            int gk = k0 + kk;
            uint4 q; q.x = q.y = q.z = q.w = 0u;
            if (gk < n) q = *(const uint4*)(h + (size_t)gk * 128 + fs);
            const unsigned short* u = (const unsigned short*)&q;
            #pragma unroll
            for (int i = 0; i < 8; ++i)
                *((unsigned short*)&hsT[fs + i][kk]) = u[i];
        }
        __syncthreads();
        short8 af0 = *(const short8*)(&hsT[wave * 32 + lrow][quad * 8]);
        short8 af1 = *(const short8*)(&hsT[wave * 32 + 16 + lrow][quad * 8]);
        #pragma unroll
        for (int t = 0; t < 8; ++t) {
            short8 bfrag = *(const short8*)(&hsT[t * 16 + lrow][quad * 8]);
            acc[0][t] = __builtin_amdgcn_mfma_f32_16x16x32_bf16(af0, bfrag, acc[0][t], 0, 0, 0);
            acc[1][t] = __builtin_amdgcn_mfma_f32_16x16x32_bf16(af1, bfrag, acc[1][t], 0, 0, 0);
        }
        __syncthreads();
    }
    float* p = partial + (size_t)b * 16384;
    #pragma unroll
    for (int a_ = 0; a_ < 2; ++a_) {
        #pragma unroll
        for (int t = 0; t < 8; ++t) {
            #pragma unroll
            for (int rr = 0; rr < 4; ++rr) {
                int gm = wave * 32 + a_ * 16 + quad * 4 + rr;
                int gn = t * 16 + lrow;
                p[gm * 128 + gn] = acc[a_][t][rr];
            }
        }
    }
}

__global__ void reduce_kernel(const float* __restrict__ partial, float* __restrict__ out, int nchunks) {
    int idx = blockIdx.x * blockDim.x + threadIdx.x;
    float s = 0.0f;
    for (int c = 0; c < nchunks; ++c) s += partial[(size_t)c * 16384 + idx];
    int i = idx / 128, j = idx % 128;
    out[idx] = (i == j) ? 0.0f : s;
}

// ---------------- launch ----------------
extern "C" void kernel_launch(void* const* d_in, const int* in_sizes, int n_in,
                              void* d_out, int out_size, void* d_ws, size_t ws_size,
                              hipStream_t stream) {
    const float* x  = (const float*)d_in[0];
    const int*   ei = (const int*)d_in[1];
    const float* ea = (const float*)d_in[2];
    const float* W[5];  const float* bvec[5];
    for (int l = 0; l < 5; ++l) { W[l] = (const float*)d_in[3 + 2 * l]; bvec[l] = (const float*)d_in[4 + 2 * l]; }
    const float* g[4]; const float* be[4]; const float* mm[4]; const float* vv[4];
    for (int l = 0; l < 4; ++l) {
        g[l]  = (const float*)d_in[13 + 4 * l];
        be[l] = (const float*)d_in[14 + 4 * l];
        mm[l] = (const float*)d_in[15 + 4 * l];
        vv[l] = (const float*)d_in[16 + 4 * l];
    }
    const int n = in_sizes[0] / NSF;        // 20000
    const int E = in_sizes[1] / 2;          // 500000
    const int EN = E + n;
    const int rsize = (n + NR - 1) / NR;
    const int total = n * NR;
    const int nscan = (total + SCK - 1) / SCK;
    const int dims[6] = {128, 256, 512, 256, 128, 128};
    const int wtoff[5] = {0, 32768, 163840, 294912, 327680};
    const int wtelems = 344064;

    // workspace layout (256B aligned); ~69 MB (identical to known-good round-1 layout)
    auto align = [](size_t o) { return (o + 255) & ~(size_t)255; };
    size_t off = 0;
    float* dinv    = (float*)((char*)d_ws + off); off = align(off + (size_t)n * 4);
    int*   fill    = (int*)  ((char*)d_ws + off); off = align(off + (size_t)total * 4);
    int*   row_ptr = (int*)  ((char*)d_ws + off); off = align(off + ((size_t)total + 1) * 4);
    int*   blksum  = (int*)  ((char*)d_ws + off); off = align(off + (size_t)256 * 4);
    int*   locb    = (int*)  ((char*)d_ws + off); off = align(off + (size_t)EN * 4);
    int2*  e8      = (int2*) ((char*)d_ws + off); off = align(off + (size_t)EN * 8);
    int*   csr_col = (int*)  ((char*)d_ws + off); off = align(off + (size_t)EN * 4);
    bf16*  wtbuf   = (bf16*) ((char*)d_ws + off); off = align(off + (size_t)wtelems * 2);
    fp8*   xq      = (fp8*)  ((char*)d_ws + off); off = align(off + (size_t)n * 128);
    bf16*  hbuf    = (bf16*) ((char*)d_ws + off); off = align(off + (size_t)n * 512 * 2);
    bf16*  abuf    = (bf16*) ((char*)d_ws + off); off = align(off + (size_t)n * 512 * 2);
    fp8*   f8buf   = (fp8*)  ((char*)d_ws + off); off = align(off + (size_t)n * 256);
    const int KCH = (20000 + 255) / 256;    // 79
    float* partial = (float*)((char*)d_ws + off); off = align(off + (size_t)KCH * 16384 * 4);

    // fused prep: zero fill + x->fp8 + W->Wt (one launch, independent of edges)
    {
        int xcnt = n * 128;
        int items = total + xcnt + wtelems;
        prep_kernel<<<(items + 255) / 256, 256, 0, stream>>>(fill, total, x, xq, xcnt,
            W[0], W[1], W[2], W[3], W[4], wtbuf, wtelems);
    }

    // CSR build (1 atomic/edge, packed edge records)
    passA_kernel<<<(EN + 255) / 256, 256, 0, stream>>>(ei, fill, locb, E, n, rsize);
    scan1_kernel<<<nscan, 256, 0, stream>>>(fill, blksum, total);
    scan2_kernel<<<1, 256, 0, stream>>>(blksum, row_ptr, nscan, total);
    scan3_kernel<<<nscan, 256, 0, stream>>>(fill, blksum, row_ptr, total);
    passB_kernel<<<(EN + 255) / 256, 256, 0, stream>>>(ei, ea, row_ptr, locb,
                                                       e8, csr_col, E, n, rsize);
    degdinv_kernel<<<(n + 255) / 256, 256, 0, stream>>>(row_ptr, e8, dinv, n);
    normw_kernel<<<(EN + 255) / 256, 256, 0, stream>>>(dinv, csr_col, e8, EN);

    int ablocks = (n + 3) / 4;
    auto gemm_bf16 = [&](const bf16* A, int l, bf16* C, int mode) {
        int K = dims[l], N = dims[l + 1];
        dim3 gg((n + 63) / 64, N / 128);
        int bi = (l < 4) ? l : 0;
        mfma_gemm_kernel<bf16><<<gg, 256, 0, stream>>>(A, wtbuf + wtoff[l], C, n, K, N, mode,
                                                       bvec[l], g[bi], be[bi], mm[bi], vv[bi]);
    };
    auto gemm_fp8 = [&](const bf16* A, int l, fp8* C, int mode) {
        int K = dims[l], N = dims[l + 1];
        dim3 gg((n + 63) / 64, N / 128);
        int bi = (l < 4) ? l : 0;
        mfma_gemm_kernel<fp8><<<gg, 256, 0, stream>>>(A, wtbuf + wtoff[l], C, n, K, N, mode,
                                                      bvec[l], g[bi], be[bi], mm[bi], vv[bi]);
    };

    // L1 (128->256): agg-first fp8 128 (xq), GEMM1 fused act -> fp8 h1
    agg_fp8_kernel<2><<<ablocks, 256, 0, stream>>>(xq, row_ptr, e8,
        bvec[0], bvec[0], bvec[0], bvec[0], bvec[0], abuf, n, 0);
    gemm_fp8(abuf, 0, f8buf, 1);
    // L2 (256->512): agg-first fp8 256 (h1) -> bf16, GEMM2 fused act -> bf16 h2 (512)
    agg_fp8_kernel<4><<<ablocks, 256, 0, stream>>>(f8buf, row_ptr, e8,
        bvec[1], bvec[1], bvec[1], bvec[1], bvec[1], abuf, n, 0);
    gemm_bf16(abuf, 1, hbuf, 1);
    // L3 (512->256): GEMM3 raw -> fp8 hw3, agg-last fp8 256 + bias+BN+sigmoid -> bf16 h3
    gemm_fp8(hbuf, 2, f8buf, 0);
    agg_fp8_kernel<4><<<ablocks, 256, 0, stream>>>(f8buf, row_ptr, e8,
        bvec[2], g[2], be[2], mm[2], vv[2], abuf, n, 1);
    // L4 (256->128): GEMM4 raw -> fp8 hw4, agg-last fp8 128 + bias+BN+sigmoid -> bf16 h4
    gemm_fp8(abuf, 3, f8buf, 0);
    agg_fp8_kernel<2><<<ablocks, 256, 0, stream>>>(f8buf, row_ptr, e8,
        bvec[3], g[3], be[3], mm[3], vv[3], hbuf, n, 1);
    // L5 (128->128): GEMM5 raw -> fp8 hw5, agg-last fp8 128 + bias+sigmoid -> bf16 h5
    gemm_fp8(hbuf, 4, f8buf, 0);
    agg_fp8_kernel<2><<<ablocks, 256, 0, stream>>>(f8buf, row_ptr, e8,
        bvec[4], bvec[4], bvec[4], bvec[4], bvec[4], abuf, n, 2);

    // final h^T h with zeroed diagonal (MFMA)
    htht_mfma_kernel<<<KCH, 256, 0, stream>>>(abuf, partial, n);
    reduce_kernel<<<16384 / 256, 256, 0, stream>>>(partial, (float*)d_out, KCH);
}

// Round 12
// 371.017 us; speedup vs baseline: 2.0048x; 1.0385x over previous
//
#include <hip/hip_runtime.h>
#include <hip/hip_bf16.h>
#include <hip/hip_fp8.h>
#include <cstdint>
#include <cstddef>
#include <cstring>

typedef __hip_bfloat16 bf16;
typedef unsigned char fp8;                                  // e4m3 storage
typedef __attribute__((ext_vector_type(8))) short short8;   // 8 bf16 (MFMA A/B frag)
typedef __attribute__((ext_vector_type(4))) float f32x4;    // MFMA C/D frag
typedef __attribute__((ext_vector_type(2))) float f32x2;

#define NSF 128
#define BN_EPS 1e-3f
#define NR 4            // src ranges per node
#define SCK 2048        // elements per scan block

// ---------------- CSR build: 1 atomic per edge ----------------

__global__ void passA_kernel(const int* __restrict__ ei, int* __restrict__ fill,
                             int* __restrict__ loc, int E, int n, int rsize) {
    int idx = blockIdx.x * blockDim.x + threadIdx.x;
    if (idx < E) {
        int r = ei[idx];
        int c = ei[E + idx];
        int slot = c * NR + r / rsize;
        loc[idx] = atomicAdd(&fill[slot], 1);
    } else if (idx < E + n) {
        int i = idx - E;
        int slot = i * NR + i / rsize;
        loc[idx] = atomicAdd(&fill[slot], 1);
    }
}

// ---- hierarchical exclusive scan of fill -> row_ptr ----

__global__ void scan1_kernel(const int* __restrict__ cnt, int* __restrict__ blksum, int total) {
    __shared__ int red[256];
    int base = blockIdx.x * SCK + threadIdx.x * 8;
    int s = 0;
    #pragma unroll
    for (int i = 0; i < 8; ++i) {
        int idx = base + i;
        if (idx < total) s += cnt[idx];
    }
    red[threadIdx.x] = s;
    __syncthreads();
    for (int off2 = 128; off2 > 0; off2 >>= 1) {
        if (threadIdx.x < off2) red[threadIdx.x] += red[threadIdx.x + off2];
        __syncthreads();
    }
    if (threadIdx.x == 0) blksum[blockIdx.x] = red[0];
}

__global__ void scan2_kernel(int* __restrict__ blksum, int* __restrict__ row_ptr,
                             int nblk, int total) {
    __shared__ int part[256];
    int tid = threadIdx.x;
    int v = (tid < nblk) ? blksum[tid] : 0;
    part[tid] = v;
    __syncthreads();
    for (int off2 = 1; off2 < 256; off2 <<= 1) {
        int t = (tid >= off2) ? part[tid - off2] : 0;
        __syncthreads();
        part[tid] += t;
        __syncthreads();
    }
    if (tid < nblk) blksum[tid] = part[tid] - v;
    if (tid == 255) row_ptr[total] = part[255];
}

__global__ void scan3_kernel(const int* __restrict__ cnt, const int* __restrict__ blkoff,
                             int* __restrict__ row_ptr, int total) {
    __shared__ int part[256];
    int tid = threadIdx.x;
    int base = blockIdx.x * SCK + tid * 8;
    int loc[8]; int s = 0;
    #pragma unroll
    for (int i = 0; i < 8; ++i) {
        int idx = base + i;
        loc[i] = (idx < total) ? cnt[idx] : 0;
        s += loc[i];
    }
    part[tid] = s;
    __syncthreads();
    for (int off2 = 1; off2 < 256; off2 <<= 1) {
        int t = (tid >= off2) ? part[tid - off2] : 0;
        __syncthreads();
        part[tid] += t;
        __syncthreads();
    }
    int run = blkoff[blockIdx.x] + part[tid] - s;
    #pragma unroll
    for (int i = 0; i < 8; ++i) {
        int idx = base + i;
        if (idx < total) { row_ptr[idx] = run; run += loc[i]; }
    }
}

// passB: scatter without atomics; packed edge record {src, w_bits}
__global__ void passB_kernel(const int* __restrict__ ei, const float* __restrict__ ea,
                             const int* __restrict__ row_ptr, const int* __restrict__ loc,
                             int2* __restrict__ e8, int* __restrict__ csr_col,
                             int E, int n, int rsize) {
    int idx = blockIdx.x * blockDim.x + threadIdx.x;
    if (idx < E) {
        int r = ei[idx];
        int c = ei[E + idx];
        int slot = c * NR + r / rsize;
        int p = row_ptr[slot] + loc[idx];
        int2 rec; rec.x = r; rec.y = __float_as_int(ea[idx]);
        e8[p] = rec;
        csr_col[p] = c;
    } else if (idx < E + n) {
        int i = idx - E;
        int slot = i * NR + i / rsize;
        int p = row_ptr[slot] + loc[idx];
        int2 rec; rec.x = i; rec.y = __float_as_int(1.0f);
        e8[p] = rec;
        csr_col[p] = i;
    }
}

__global__ void degdinv_kernel(const int* __restrict__ row_ptr, const int2* __restrict__ e8,
                               float* __restrict__ dinv, int n) {
    int node = blockIdx.x * blockDim.x + threadIdx.x;
    if (node < n) {
        int s = row_ptr[node * NR], e = row_ptr[(node + 1) * NR];
        float d = 0.0f;
        for (int j = s; j < e; ++j) d += __int_as_float(e8[j].y);
        dinv[node] = (d > 0.0f) ? rsqrtf(d) : 0.0f;
    }
}

__global__ void normw_kernel(const float* __restrict__ dinv, const int* __restrict__ csr_col,
                             int2* __restrict__ e8, int EN) {
    int p = blockIdx.x * blockDim.x + threadIdx.x;
    if (p < EN) {
        int2 rec = e8[p];
        float w = dinv[rec.x] * __int_as_float(rec.y) * dinv[csr_col[p]];
        ((int*)e8)[2 * p + 1] = __float_as_int(w);
    }
}

// ---------------- output-type helpers (HW fp8 cvt) ----------------

__device__ inline void store_val(bf16* C, size_t idx, float a) {
    C[idx] = __float2bfloat16(a);
}
__device__ inline void store_val(fp8* C, size_t idx, float a) {
    int packed = __builtin_amdgcn_cvt_pk_fp8_f32(a, a, 0, false);
    C[idx] = (fp8)(packed & 0xff);
}

// ---------------- fused prep: zero fill[] + x->fp8 + all W->Wt(bf16), one launch ----------------
__global__ void prep_kernel(int* __restrict__ fill, int total,
                            const float* __restrict__ x, fp8* __restrict__ xq, int xcnt,
                            const float* __restrict__ W0, const float* __restrict__ W1,
                            const float* __restrict__ W2, const float* __restrict__ W3,
                            const float* __restrict__ W4,
                            bf16* __restrict__ wtbuf, int wtelems) {
    int idx = blockIdx.x * blockDim.x + threadIdx.x;
    if (idx < total) { fill[idx] = 0; return; }
    idx -= total;
    if (idx < xcnt) {
        store_val(xq, idx, x[idx]);
        return;
    }
    int widx = idx - xcnt;
    if (widx >= wtelems) return;
    // layer boundaries (cumulative K*N): 32768, 163840, 294912, 327680, 344064
    const float* W; int K, off;
    if (widx < 32768)       { W = W0; K = 128; off = 0; }
    else if (widx < 163840) { W = W1; K = 256; off = 32768; }
    else if (widx < 294912) { W = W2; K = 512; off = 163840; }
    else if (widx < 327680) { W = W3; K = 256; off = 294912; }
    else                    { W = W4; K = 128; off = 327680; }
    int N2;
    if (widx < 32768) N2 = 256; else if (widx < 163840) N2 = 512;
    else if (widx < 294912) N2 = 256; else N2 = 128;
    int l = widx - off;
    int nn = l / K, kk = l % K;
    wtbuf[widx] = __float2bfloat16(W[(size_t)kk * N2 + nn]);
}

// ---------------- direct global->LDS 16B staging ----------------

__device__ inline void gl_lds16(const bf16* g, bf16* l) {
    __builtin_amdgcn_global_load_lds(
        (const __attribute__((address_space(1))) void*)g,
        (__attribute__((address_space(3))) void*)l,
        16, 0, 0);
}

// ---------------- MFMA GEMM (64x128 tile, BK=64 dual-stage): C = A @ Wt^T ----------------
// mode 0: raw store; mode 1: sigmoid(BN(acc+bias))

template <typename OT>
__global__ __launch_bounds__(256) void mfma_gemm_kernel(
    const bf16* __restrict__ A, const bf16* __restrict__ Wt,
    OT* __restrict__ C, int M, int K, int N, int mode,
    const float* __restrict__ bias, const float* __restrict__ g,
    const float* __restrict__ be, const float* __restrict__ m,
    const float* __restrict__ v) {
    __shared__ bf16 As[2][64][32];
    __shared__ bf16 Bs[2][128][32];
    int m0 = blockIdx.x * 64;
    int n0 = blockIdx.y * 128;
    int tid = threadIdx.x;
    int wave = tid >> 6, lane = tid & 63;
    int lrow = lane & 15, quad = lane >> 4;

    f32x4 acc[4][2] = {};   // [m-tile][n-tile]

    int srow = lane >> 2;
    int sseg = lane & 3;
    int am = wave * 16 + srow;
    int bn = wave * 32 + srow;
    bool aok = (m0 + am) < M;

    for (int k0 = 0; k0 < K; k0 += 64) {
        if (aok) {
            gl_lds16(A + (size_t)(m0 + am) * K + k0 + sseg * 8,      &As[0][am][sseg * 8]);
            gl_lds16(A + (size_t)(m0 + am) * K + k0 + 32 + sseg * 8, &As[1][am][sseg * 8]);
        }
        gl_lds16(Wt + (size_t)(n0 + bn) * K + k0 + sseg * 8,           &Bs[0][bn][sseg * 8]);
        gl_lds16(Wt + (size_t)(n0 + bn) * K + k0 + 32 + sseg * 8,      &Bs[1][bn][sseg * 8]);
        gl_lds16(Wt + (size_t)(n0 + bn + 16) * K + k0 + sseg * 8,      &Bs[0][bn + 16][sseg * 8]);
        gl_lds16(Wt + (size_t)(n0 + bn + 16) * K + k0 + 32 + sseg * 8, &Bs[1][bn + 16][sseg * 8]);
        __syncthreads();

        #pragma unroll
        for (int ks = 0; ks < 2; ++ks) {
            short8 afrag[4], bfrag[2];
            #pragma unroll
            for (int mt = 0; mt < 4; ++mt)
                afrag[mt] = *(const short8*)(&As[ks][mt * 16 + lrow][quad * 8]);
            #pragma unroll
            for (int nt = 0; nt < 2; ++nt)
                bfrag[nt] = *(const short8*)(&Bs[ks][wave * 32 + nt * 16 + lrow][quad * 8]);
            #pragma unroll
            for (int mt = 0; mt < 4; ++mt)
                #pragma unroll
                for (int nt = 0; nt < 2; ++nt)
                    acc[mt][nt] = __builtin_amdgcn_mfma_f32_16x16x32_bf16(
                        afrag[mt], bfrag[nt], acc[mt][nt], 0, 0, 0);
        }
        __syncthreads();
    }
    // C/D: col = lane&15, row = quad*4 + reg
    #pragma unroll
    for (int nt = 0; nt < 2; ++nt) {
        int gn = n0 + wave * 32 + nt * 16 + lrow;
        float bsc = 0.0f, scale = 1.0f, mean = 0.0f, beta = 0.0f;
        if (mode == 1) {
            bsc = bias[gn];
            scale = g[gn] * rsqrtf(v[gn] + BN_EPS);
            mean = m[gn];
            beta = be[gn];
        }
        #pragma unroll
        for (int mt = 0; mt < 4; ++mt) {
            #pragma unroll
            for (int rr = 0; rr < 4; ++rr) {
                int gm = m0 + mt * 16 + quad * 4 + rr;
                if (gm < M) {
                    float a = acc[mt][nt][rr];
                    if (mode == 1) {
                        a = (a + bsc - mean) * scale + beta;
                        a = 1.0f / (1.0f + __expf(-a));
                    }
                    store_val(C, (size_t)gm * N + gn, a);
                }
            }
        }
    }
}

// ---------------- fp8 aggregation: 2 nodes/wave, cross-node record-latency hiding ----------------
// Round 28: each wave owns nodes nA,nB. Both nodes' chunk-0 record loads are issued
// back-to-back at the top (2 coalesced loads in flight), ONE fence covers both; B's
// record latency hides under A's gather phase. Gather pipeline itself is the round-8
// known-good A/B 8-group structure with full 64-lane records.

template <int VEC> struct F8Vec;
template <> struct F8Vec<2> { typedef unsigned short T; };
template <> struct F8Vec<4> { typedef unsigned int T; };

__device__ inline void fma_f8(unsigned short q, float w, float* acc) {
    f32x2 lo = __builtin_amdgcn_cvt_pk_f32_fp8((unsigned int)q, false);
    acc[0] += w * lo.x;
    acc[1] += w * lo.y;
}
__device__ inline void fma_f8(unsigned int q, float w, float* acc) {
    f32x2 lo = __builtin_amdgcn_cvt_pk_f32_fp8(q, false);
    f32x2 hi = __builtin_amdgcn_cvt_pk_f32_fp8(q, true);
    acc[0] += w * lo.x;
    acc[1] += w * lo.y;
    acc[2] += w * hi.x;
    acc[3] += w * hi.y;
}

template <int VEC>
__global__ __launch_bounds__(256) void agg_fp8_kernel(
    const fp8* __restrict__ hw,
    const int* __restrict__ row_ptr, const int2* __restrict__ e8,
    const float* __restrict__ bias,
    const float* __restrict__ g, const float* __restrict__ be,
    const float* __restrict__ m, const float* __restrict__ v,
    bf16* __restrict__ out, int n, int mode) {
    typedef typename F8Vec<VEC>::T T;
    const int dfeat = VEC * 64;
    __shared__ int2 recs[4][2][64];
    int wave = threadIdx.x >> 6;
    int lane = threadIdx.x & 63;
    int nA = blockIdx.x * 8 + wave * 2;
    int nB = nA + 1;
    if (nA >= n) return;
    bool hasB = (nB < n);
    int sA = row_ptr[nA * NR], eA = row_ptr[(nA + 1) * NR];
    int sB = hasB ? row_ptr[nB * NR] : 0, eB = hasB ? row_ptr[(nB + 1) * NR] : 0;
    const unsigned int base = (unsigned int)lane * VEC;

    // issue BOTH nodes' chunk-0 record loads back-to-back, one fence
    {
        int cntA0 = eA - sA; if (cntA0 > 64) cntA0 = 64;
        int cntB0 = eB - sB; if (cntB0 > 64) cntB0 = 64;
        int2 rA; rA.x = 0; rA.y = 0;
        int2 rB; rB.x = 0; rB.y = 0;
        if (lane < cntA0) rA = e8[sA + lane];
        if (hasB && lane < cntB0) rB = e8[sB + lane];
        recs[wave][0][lane] = rA;
        recs[wave][1][lane] = rB;
        asm volatile("s_waitcnt vmcnt(0) lgkmcnt(0)" ::: "memory");
    }

#define LOADG(Q, WV, SLOT, J0)                                               \
    _Pragma("unroll")                                                        \
    for (int u = 0; u < 8; ++u) {                                            \
        int2 rec = recs[wave][SLOT][(J0) + u];                               \
        WV[u] = __int_as_float(rec.y);                                       \
        Q[u] = *(const T*)(hw + ((unsigned int)rec.x * dfeat + base));       \
    }
#define CONSUME(Q, WV)                                                       \
    _Pragma("unroll")                                                        \
    for (int u = 0; u < 8; ++u) fma_f8(Q[u], WV[u], acc);

// process one chunk already staged in recs[wave][SLOT]
#define PROC_CHUNK(SLOT, CNT)                                                \
    {                                                                        \
        int npad = ((CNT) + 15) & ~15;                                       \
        T qA[8], qB[8];                                                      \
        float wA[8], wB[8];                                                  \
        LOADG(qA, wA, SLOT, 0)                                               \
        LOADG(qB, wB, SLOT, 8)                                               \
        for (int j0 = 16; j0 < npad; j0 += 16) {                             \
            CONSUME(qA, wA)                                                  \
            LOADG(qA, wA, SLOT, j0)                                          \
            CONSUME(qB, wB)                                                  \
            LOADG(qB, wB, SLOT, j0 + 8)                                      \
        }                                                                    \
        CONSUME(qA, wA)                                                      \
        CONSUME(qB, wB)                                                      \
    }

// stage chunk starting at CS into recs[wave][SLOT] (blunt fence), for tail chunks
#define STAGE_CHUNK(SLOT, CS, CE)                                            \
    {                                                                        \
        int cnt2 = (CE) - (CS); if (cnt2 > 64) cnt2 = 64;                    \
        int2 r0; r0.x = 0; r0.y = 0;                                         \
        if (lane < cnt2) r0 = e8[(CS) + lane];                               \
        recs[wave][SLOT][lane] = r0;                                         \
        asm volatile("s_waitcnt vmcnt(0) lgkmcnt(0)" ::: "memory");          \
    }

    float acc[VEC];
    // ---- node A ----
    #pragma unroll
    for (int i = 0; i < VEC; ++i) acc[i] = 0.0f;
    {
        int cnt0 = eA - sA; if (cnt0 > 64) cnt0 = 64;
        PROC_CHUNK(0, cnt0)
        for (int cs = sA + 64; cs < eA; cs += 64) {
            STAGE_CHUNK(0, cs, eA)
            int cnt2 = eA - cs; if (cnt2 > 64) cnt2 = 64;
            PROC_CHUNK(0, cnt2)
        }
    }
    #pragma unroll
    for (int i = 0; i < VEC; ++i) {
        int f = (int)base + i;
        float a = acc[i];
        if (mode != 0) {
            a += bias[f];
            if (mode == 1) {
                float scale = g[f] * rsqrtf(v[f] + BN_EPS);
                a = (a - m[f]) * scale + be[f];
            }
            a = 1.0f / (1.0f + __expf(-a));
        }
        out[(size_t)nA * dfeat + f] = __float2bfloat16(a);
    }

    // ---- node B (records already resident in LDS; latency hidden under A) ----
    if (hasB) {
        #pragma unroll
        for (int i = 0; i < VEC; ++i) acc[i] = 0.0f;
        int cnt0 = eB - sB; if (cnt0 > 64) cnt0 = 64;
        PROC_CHUNK(1, cnt0)
        for (int cs = sB + 64; cs < eB; cs += 64) {
            STAGE_CHUNK(1, cs, eB)
            int cnt2 = eB - cs; if (cnt2 > 64) cnt2 = 64;
            PROC_CHUNK(1, cnt2)
        }
        #pragma unroll
        for (int i = 0; i < VEC; ++i) {
            int f = (int)base + i;
            float a = acc[i];
            if (mode != 0) {
                a += bias[f];
                if (mode == 1) {
                    float scale = g[f] * rsqrtf(v[f] + BN_EPS);
                    a = (a - m[f]) * scale + be[f];
                }
                a = 1.0f / (1.0f + __expf(-a));
            }
            out[(size_t)nB * dfeat + f] = __float2bfloat16(a);
        }
    }
#undef LOADG
#undef CONSUME
#undef PROC_CHUNK
#undef STAGE_CHUNK
}

// ---------------- final h^T h via MFMA ----------------
#define TPAD 8

__global__ __launch_bounds__(256) void htht_mfma_kernel(
    const bf16* __restrict__ h, float* __restrict__ partial, int n) {
    __shared__ bf16 hsT[128][32 + TPAD];
    int b = blockIdx.x;
    int tid = threadIdx.x;
    int wave = tid >> 6, lane = tid & 63;
    int lrow = lane & 15, quad = lane >> 4;

    f32x4 acc[2][8] = {};

    int kk = tid >> 3;
    int seg = tid & 7;

    for (int kt = 0; kt < 8; ++kt) {
        int k0 = b * 256 + kt * 32;
        #pragma unroll
        for (int s2 = 0; s2 < 2; ++s2) {
            int fs = (seg + s2 * 8) * 8;
            int gk = k0 + kk;
            uint4 q; q.x = q.y = q.z = q.w = 0u;
            if (gk < n) q = *(const uint4*)(h + (size_t)gk * 128 + fs);
            const unsigned short* u = (const unsigned short*)&q;
            #pragma unroll
            for (int i = 0; i < 8; ++i)
                *((unsigned short*)&hsT[fs + i][kk]) = u[i];
        }
        __syncthreads();
        short8 af0 = *(const short8*)(&hsT[wave * 32 + lrow][quad * 8]);
        short8 af1 = *(const short8*)(&hsT[wave * 32 + 16 + lrow][quad * 8]);
        #pragma unroll
        for (int t = 0; t < 8; ++t) {
            short8 bfrag = *(const short8*)(&hsT[t * 16 + lrow][quad * 8]);
            acc[0][t] = __builtin_amdgcn_mfma_f32_16x16x32_bf16(af0, bfrag, acc[0][t], 0, 0, 0);
            acc[1][t] = __builtin_amdgcn_mfma_f32_16x16x32_bf16(af1, bfrag, acc[1][t], 0, 0, 0);
        }
        __syncthreads();
    }
    float* p = partial + (size_t)b * 16384;
    #pragma unroll
    for (int a_ = 0; a_ < 2; ++a_) {
        #pragma unroll
        for (int t = 0; t < 8; ++t) {
            #pragma unroll
            for (int rr = 0; rr < 4; ++rr) {
                int gm = wave * 32 + a_ * 16 + quad * 4 + rr;
                int gn = t * 16 + lrow;
                p[gm * 128 + gn] = acc[a_][t][rr];
            }
        }
    }
}

__global__ void reduce_kernel(const float* __restrict__ partial, float* __restrict__ out, int nchunks) {
    int idx = blockIdx.x * blockDim.x + threadIdx.x;
    float s = 0.0f;
    for (int c = 0; c < nchunks; ++c) s += partial[(size_t)c * 16384 + idx];
    int i = idx / 128, j = idx % 128;
    out[idx] = (i == j) ? 0.0f : s;
}

// ---------------- launch ----------------
extern "C" void kernel_launch(void* const* d_in, const int* in_sizes, int n_in,
                              void* d_out, int out_size, void* d_ws, size_t ws_size,
                              hipStream_t stream) {
    const float* x  = (const float*)d_in[0];
    const int*   ei = (const int*)d_in[1];
    const float* ea = (const float*)d_in[2];
    const float* W[5];  const float* bvec[5];
    for (int l = 0; l < 5; ++l) { W[l] = (const float*)d_in[3 + 2 * l]; bvec[l] = (const float*)d_in[4 + 2 * l]; }
    const float* g[4]; const float* be[4]; const float* mm[4]; const float* vv[4];
    for (int l = 0; l < 4; ++l) {
        g[l]  = (const float*)d_in[13 + 4 * l];
        be[l] = (const float*)d_in[14 + 4 * l];
        mm[l] = (const float*)d_in[15 + 4 * l];
        vv[l] = (const float*)d_in[16 + 4 * l];
    }
    const int n = in_sizes[0] / NSF;        // 20000
    const int E = in_sizes[1] / 2;          // 500000
    const int EN = E + n;
    const int rsize = (n + NR - 1) / NR;
    const int total = n * NR;
    const int nscan = (total + SCK - 1) / SCK;
    const int dims[6] = {128, 256, 512, 256, 128, 128};
    const int wtoff[5] = {0, 32768, 163840, 294912, 327680};
    const int wtelems = 344064;

    // workspace layout (256B aligned); ~69 MB (identical to known-good round-1 layout)
    auto align = [](size_t o) { return (o + 255) & ~(size_t)255; };
    size_t off = 0;
    float* dinv    = (float*)((char*)d_ws + off); off = align(off + (size_t)n * 4);
    int*   fill    = (int*)  ((char*)d_ws + off); off = align(off + (size_t)total * 4);
    int*   row_ptr = (int*)  ((char*)d_ws + off); off = align(off + ((size_t)total + 1) * 4);
    int*   blksum  = (int*)  ((char*)d_ws + off); off = align(off + (size_t)256 * 4);
    int*   locb    = (int*)  ((char*)d_ws + off); off = align(off + (size_t)EN * 4);
    int2*  e8      = (int2*) ((char*)d_ws + off); off = align(off + (size_t)EN * 8);
    int*   csr_col = (int*)  ((char*)d_ws + off); off = align(off + (size_t)EN * 4);
    bf16*  wtbuf   = (bf16*) ((char*)d_ws + off); off = align(off + (size_t)wtelems * 2);
    fp8*   xq      = (fp8*)  ((char*)d_ws + off); off = align(off + (size_t)n * 128);
    bf16*  hbuf    = (bf16*) ((char*)d_ws + off); off = align(off + (size_t)n * 512 * 2);
    bf16*  abuf    = (bf16*) ((char*)d_ws + off); off = align(off + (size_t)n * 512 * 2);
    fp8*   f8buf   = (fp8*)  ((char*)d_ws + off); off = align(off + (size_t)n * 256);
    const int KCH = (20000 + 255) / 256;    // 79
    float* partial = (float*)((char*)d_ws + off); off = align(off + (size_t)KCH * 16384 * 4);

    // fused prep: zero fill + x->fp8 + W->Wt (one launch, independent of edges)
    {
        int xcnt = n * 128;
        int items = total + xcnt + wtelems;
        prep_kernel<<<(items + 255) / 256, 256, 0, stream>>>(fill, total, x, xq, xcnt,
            W[0], W[1], W[2], W[3], W[4], wtbuf, wtelems);
    }

    // CSR build (1 atomic/edge, packed edge records)
    passA_kernel<<<(EN + 255) / 256, 256, 0, stream>>>(ei, fill, locb, E, n, rsize);
    scan1_kernel<<<nscan, 256, 0, stream>>>(fill, blksum, total);
    scan2_kernel<<<1, 256, 0, stream>>>(blksum, row_ptr, nscan, total);
    scan3_kernel<<<nscan, 256, 0, stream>>>(fill, blksum, row_ptr, total);
    passB_kernel<<<(EN + 255) / 256, 256, 0, stream>>>(ei, ea, row_ptr, locb,
                                                       e8, csr_col, E, n, rsize);
    degdinv_kernel<<<(n + 255) / 256, 256, 0, stream>>>(row_ptr, e8, dinv, n);
    normw_kernel<<<(EN + 255) / 256, 256, 0, stream>>>(dinv, csr_col, e8, EN);

    int ablocks = (n + 7) / 8;
    auto gemm_bf16 = [&](const bf16* A, int l, bf16* C, int mode) {
        int K = dims[l], N = dims[l + 1];
        dim3 gg((n + 63) / 64, N / 128);
        int bi = (l < 4) ? l : 0;
        mfma_gemm_kernel<bf16><<<gg, 256, 0, stream>>>(A, wtbuf + wtoff[l], C, n, K, N, mode,
                                                       bvec[l], g[bi], be[bi], mm[bi], vv[bi]);
    };
    auto gemm_fp8 = [&](const bf16* A, int l, fp8* C, int mode) {
        int K = dims[l], N = dims[l + 1];
        dim3 gg((n + 63) / 64, N / 128);
        int bi = (l < 4) ? l : 0;
        mfma_gemm_kernel<fp8><<<gg, 256, 0, stream>>>(A, wtbuf + wtoff[l], C, n, K, N, mode,
                                                      bvec[l], g[bi], be[bi], mm[bi], vv[bi]);
    };

    // L1 (128->256): agg-first fp8 128 (xq), GEMM1 fused act -> fp8 h1
    agg_fp8_kernel<2><<<ablocks, 256, 0, stream>>>(xq, row_ptr, e8,
        bvec[0], bvec[0], bvec[0], bvec[0], bvec[0], abuf, n, 0);
    gemm_fp8(abuf, 0, f8buf, 1);
    // L2 (256->512): agg-first fp8 256 (h1) -> bf16, GEMM2 fused act -> bf16 h2 (512)
    agg_fp8_kernel<4><<<ablocks, 256, 0, stream>>>(f8buf, row_ptr, e8,
        bvec[1], bvec[1], bvec[1], bvec[1], bvec[1], abuf, n, 0);
    gemm_bf16(abuf, 1, hbuf, 1);
    // L3 (512->256): GEMM3 raw -> fp8 hw3, agg-last fp8 256 + bias+BN+sigmoid -> bf16 h3
    gemm_fp8(hbuf, 2, f8buf, 0);
    agg_fp8_kernel<4><<<ablocks, 256, 0, stream>>>(f8buf, row_ptr, e8,
        bvec[2], g[2], be[2], mm[2], vv[2], abuf, n, 1);
    // L4 (256->128): GEMM4 raw -> fp8 hw4, agg-last fp8 128 + bias+BN+sigmoid -> bf16 h4
    gemm_fp8(abuf, 3, f8buf, 0);
    agg_fp8_kernel<2><<<ablocks, 256, 0, stream>>>(f8buf, row_ptr, e8,
        bvec[3], g[3], be[3], mm[3], vv[3], hbuf, n, 1);
    // L5 (128->128): GEMM5 raw -> fp8 hw5, agg-last fp8 128 + bias+sigmoid -> bf16 h5
    gemm_fp8(hbuf, 4, f8buf, 0);
    agg_fp8_kernel<2><<<ablocks, 256, 0, stream>>>(f8buf, row_ptr, e8,
        bvec[4], bvec[4], bvec[4], bvec[4], bvec[4], abuf, n, 2);

    // final h^T h with zeroed diagonal (MFMA)
    htht_mfma_kernel<<<KCH, 256, 0, stream>>>(abuf, partial, n);
    reduce_kernel<<<16384 / 256, 256, 0, stream>>>(partial, (float*)d_out, KCH);
}